// Round 4
// baseline (253.156 us; speedup 1.0000x reference)
//
#include <hip/hip_runtime.h>
#include <math.h>

#define NN 2048      // nodes
#define HH 6         // heads
#define HD 768       // H*D
#define NA 32        // agents/scene
#define NB 64        // scenes
#define KC 12        // wo1 K-split chunks
#define BKW 64       // wo1 K-chunk size

__device__ __forceinline__ float dot4(float4 a, float4 b) {
    return a.x * b.x + a.y * b.y + a.z * b.z + a.w * b.w;
}

// ---------------------------------------------------------------------------
// K1: R[m] = agents @ Wm^T (raw) + per-col-block LN partials.
// Block 256 thr: tile 64 nodes x 128 cols, thread = 4n x 8c.
// A transposed in LDS ([k][node], XOR-swizzled); W streamed from global
// (8 float4 per k-quad -> 128 FMA). Grid (32, 18): y = m*6 + cb.
// ---------------------------------------------------------------------------
__global__ __launch_bounds__(256) void proj_gemm_kernel(
    const float* __restrict__ agents,
    const float* __restrict__ Wq, const float* __restrict__ Wk, const float* __restrict__ Wv,
    float* __restrict__ R,    // [3][2048][768]
    float* __restrict__ ps)   // [3][2048][6][2]
{
    __shared__ float At[128][68];   // [k][node^swz], 34 KB
    const int tid = threadIdx.x;
    const int ngb = blockIdx.x;                 // 64-node group
    const int m = blockIdx.y / 6, cb = blockIdx.y % 6;
    const int n0 = ngb * 64;
    const float* W = (m == 0) ? Wq : (m == 1) ? Wk : Wv;

    // stage A transposed: 64 nodes x 128 k  (swz = (kq&15)<<2, 4-aligned)
    {
        const float4* src = (const float4*)(agents + (size_t)n0 * 128);
        #pragma unroll
        for (int r = 0; r < 8; ++r) {
            const int i = tid + r * 256;        // 0..2047
            const int node = i >> 5, kq = i & 31;
            const float4 a = src[i];
            const int sw = (kq & 15) << 2;
            float* dst = &At[kq * 4][0];
            dst[0 * 68 + (node ^ sw)] = a.x;
            dst[1 * 68 + (node ^ sw)] = a.y;
            dst[2 * 68 + (node ^ sw)] = a.z;
            dst[3 * 68 + (node ^ sw)] = a.w;
        }
    }
    __syncthreads();

    const int cg = tid & 15, ngt = tid >> 4;
    const int colbase = cb * 128 + cg * 8;
    const float* wp = W + (size_t)colbase * 128;

    float4 acc[8];
    #pragma unroll
    for (int c = 0; c < 8; ++c) acc[c] = make_float4(0.f, 0.f, 0.f, 0.f);

    #pragma unroll 2
    for (int kq = 0; kq < 32; ++kq) {
        const int sw = (kq & 15) << 2;
        const int nb = (ngt * 4) ^ sw;
        const float4 a0 = *(const float4*)&At[kq * 4 + 0][nb];
        const float4 a1 = *(const float4*)&At[kq * 4 + 1][nb];
        const float4 a2 = *(const float4*)&At[kq * 4 + 2][nb];
        const float4 a3 = *(const float4*)&At[kq * 4 + 3][nb];
        #pragma unroll
        for (int c = 0; c < 8; ++c) {
            const float4 w = *(const float4*)(wp + (size_t)c * 128 + kq * 4);
            acc[c].x += w.x * a0.x + w.y * a1.x + w.z * a2.x + w.w * a3.x;
            acc[c].y += w.x * a0.y + w.y * a1.y + w.z * a2.y + w.w * a3.y;
            acc[c].z += w.x * a0.z + w.y * a1.z + w.z * a2.z + w.w * a3.z;
            acc[c].w += w.x * a0.w + w.y * a1.w + w.z * a2.w + w.w * a3.w;
        }
    }

    // per-node partial {sum, sumsq} over this block's 128 cols
    {
        float ssum[4] = {0.f, 0.f, 0.f, 0.f}, sq[4] = {0.f, 0.f, 0.f, 0.f};
        #pragma unroll
        for (int c = 0; c < 8; ++c) {
            ssum[0] += acc[c].x; sq[0] += acc[c].x * acc[c].x;
            ssum[1] += acc[c].y; sq[1] += acc[c].y * acc[c].y;
            ssum[2] += acc[c].z; sq[2] += acc[c].z * acc[c].z;
            ssum[3] += acc[c].w; sq[3] += acc[c].w * acc[c].w;
        }
        #pragma unroll
        for (int mask = 1; mask <= 8; mask <<= 1) {
            #pragma unroll
            for (int t = 0; t < 4; ++t) {
                ssum[t] += __shfl_xor(ssum[t], mask);
                sq[t]   += __shfl_xor(sq[t], mask);
            }
        }
        if (cg == 0) {
            #pragma unroll
            for (int t = 0; t < 4; ++t) {
                const size_t o = ((size_t)m * NN + n0 + ngt * 4 + t) * 12 + cb * 2;
                ps[o]     = ssum[t];
                ps[o + 1] = sq[t];
            }
        }
    }

    // write raw outputs (4 node rows x 8 cols)
    {
        const size_t rb = (size_t)m * NN + n0 + ngt * 4;
        #pragma unroll
        for (int c = 0; c < 8; ++c) {
            R[(rb + 0) * HD + colbase + c] = acc[c].x;
            R[(rb + 1) * HD + colbase + c] = acc[c].y;
            R[(rb + 2) * HD + colbase + c] = acc[c].z;
            R[(rb + 3) * HD + colbase + c] = acc[c].w;
        }
    }
}

// ---------------------------------------------------------------------------
// K2: per-(scene, head) attention; applies LN (q,k) and LN+relu (v) during
// LDS staging from raw R + partial stats.
// ---------------------------------------------------------------------------
__global__ __launch_bounds__(256) void attn_kernel(
    const float* __restrict__ R, const float* __restrict__ ps,
    const float* __restrict__ gq, const float* __restrict__ bq,
    const float* __restrict__ gk, const float* __restrict__ bk,
    const float* __restrict__ gv, const float* __restrict__ bv,
    float* __restrict__ O)
{
    __shared__ float Qs[32][132];
    __shared__ float Ks[32][132];
    __shared__ float Vs[32][132];
    __shared__ float Ss[32][33];
    __shared__ float stat_s[3][32][2];
    const int tid = threadIdx.x;
    const int scene = blockIdx.x, h = blockIdx.y;

    if (tid < 96) {
        const int m = tid / 32, row = tid & 31;
        const float* p = ps + ((size_t)m * NN + scene * 32 + row) * 12;
        float s = 0.f, q = 0.f;
        #pragma unroll
        for (int c = 0; c < 6; ++c) { s += p[2 * c]; q += p[2 * c + 1]; }
        const float mu = s * (1.f / 768.f);
        const float var = q * (1.f / 768.f) - mu * mu;
        stat_s[m][row][0] = mu;
        stat_s[m][row][1] = rsqrtf(var + 1e-5f);
    }
    __syncthreads();

    for (int m = 0; m < 3; ++m) {
        const float* Rm = R + (size_t)m * NN * HD;
        const float* g = (m == 0) ? gq : (m == 1) ? gk : gv;
        const float* b = (m == 0) ? bq : (m == 1) ? bk : bv;
        float* dst = (m == 0) ? &Qs[0][0] : (m == 1) ? &Ks[0][0] : &Vs[0][0];
        #pragma unroll
        for (int r = 0; r < 4; ++r) {
            const int idx = tid + r * 256;
            const int row = idx >> 5, c4 = idx & 31;
            const float4 x = *(const float4*)(Rm + ((size_t)scene * 32 + row) * HD + h * 128 + c4 * 4);
            const float mu = stat_s[m][row][0], rs = stat_s[m][row][1];
            const float4 gg = *(const float4*)(g + h * 128 + c4 * 4);
            const float4 bb = *(const float4*)(b + h * 128 + c4 * 4);
            float4 y;
            y.x = (x.x - mu) * rs * gg.x + bb.x;
            y.y = (x.y - mu) * rs * gg.y + bb.y;
            y.z = (x.z - mu) * rs * gg.z + bb.z;
            y.w = (x.w - mu) * rs * gg.w + bb.w;
            if (m == 2) {
                y.x = fmaxf(y.x, 0.f); y.y = fmaxf(y.y, 0.f);
                y.z = fmaxf(y.z, 0.f); y.w = fmaxf(y.w, 0.f);
            }
            *(float4*)(dst + row * 132 + c4 * 4) = y;
        }
    }
    __syncthreads();

    {
        const int ti = tid >> 4, tj = tid & 15;
        float a00 = 0.f, a01 = 0.f, a10 = 0.f, a11 = 0.f;
        #pragma unroll 4
        for (int k4 = 0; k4 < 32; ++k4) {
            const float4 q0 = *(const float4*)&Qs[2 * ti][k4 * 4];
            const float4 q1 = *(const float4*)&Qs[2 * ti + 1][k4 * 4];
            const float4 k0 = *(const float4*)&Ks[2 * tj][k4 * 4];
            const float4 k1 = *(const float4*)&Ks[2 * tj + 1][k4 * 4];
            a00 += dot4(q0, k0); a01 += dot4(q0, k1);
            a10 += dot4(q1, k0); a11 += dot4(q1, k1);
        }
        const float scale = 0.08838834764831845f;  // 1/sqrt(128)
        Ss[2 * ti][2 * tj]         = a00 * scale;
        Ss[2 * ti][2 * tj + 1]     = a01 * scale;
        Ss[2 * ti + 1][2 * tj]     = a10 * scale;
        Ss[2 * ti + 1][2 * tj + 1] = a11 * scale;
    }
    __syncthreads();

    {
        const int g = tid >> 5, l = tid & 31;
        #pragma unroll
        for (int ib = 0; ib < 4; ++ib) {
            const int i = g + ib * 8;
            const float sv = Ss[i][l];
            float mx = sv;
            #pragma unroll
            for (int mask = 16; mask >= 1; mask >>= 1)
                mx = fmaxf(mx, __shfl_xor(mx, mask));
            const float p = __expf(sv - mx);
            float sum = p;
            #pragma unroll
            for (int mask = 16; mask >= 1; mask >>= 1)
                sum += __shfl_xor(sum, mask);
            Ss[i][l] = p / sum;
        }
    }
    __syncthreads();

    {
        const int i = tid >> 3, dg = tid & 7;
        float o[4][4] = {};
        for (int j = 0; j < 32; ++j) {
            const float p = Ss[i][j];
            #pragma unroll
            for (int r = 0; r < 4; ++r) {
                const float4 v4 = *(const float4*)&Vs[j][dg * 4 + 32 * r];
                o[r][0] += p * v4.x; o[r][1] += p * v4.y;
                o[r][2] += p * v4.z; o[r][3] += p * v4.w;
            }
        }
        const size_t base = ((size_t)scene * 32 + i) * HD + h * 128;
        #pragma unroll
        for (int r = 0; r < 4; ++r)
            *(float4*)(O + base + dg * 4 + 32 * r) =
                make_float4(o[r][0], o[r][1], o[r][2], o[r][3]);
    }
}

// ---------------------------------------------------------------------------
// K3a: P[kc] = O[:, kc*64:+64] @ Wo1[:, same]^T  (K-split partials).
// Same template as K1: tile 64n x 128c, thread 4n x 8c. Grid (32, 12).
// ---------------------------------------------------------------------------
__global__ __launch_bounds__(256) void wo1_gemm_kernel(
    const float* __restrict__ O, const float* __restrict__ Wo1,
    float* __restrict__ P)    // [KC][2048][128]
{
    __shared__ float At[BKW][68];
    const int tid = threadIdx.x;
    const int ngb = blockIdx.x, kc = blockIdx.y;
    const int n0 = ngb * 64;

    {
        #pragma unroll
        for (int r = 0; r < 4; ++r) {
            const int i = tid + r * 256;        // 0..1023
            const int node = i >> 4, kq = i & 15;
            const float4 a = *(const float4*)(O + ((size_t)n0 + node) * HD + kc * BKW + kq * 4);
            const int sw = (kq & 15) << 2;
            float* dst = &At[kq * 4][0];
            dst[0 * 68 + (node ^ sw)] = a.x;
            dst[1 * 68 + (node ^ sw)] = a.y;
            dst[2 * 68 + (node ^ sw)] = a.z;
            dst[3 * 68 + (node ^ sw)] = a.w;
        }
    }
    __syncthreads();

    const int cg = tid & 15, ngt = tid >> 4;
    const int colbase = cg * 8;
    const float* wp = Wo1 + (size_t)colbase * HD + kc * BKW;

    float4 acc[8];
    #pragma unroll
    for (int c = 0; c < 8; ++c) acc[c] = make_float4(0.f, 0.f, 0.f, 0.f);

    #pragma unroll 2
    for (int kq = 0; kq < 16; ++kq) {
        const int sw = (kq & 15) << 2;
        const int nb = (ngt * 4) ^ sw;
        const float4 a0 = *(const float4*)&At[kq * 4 + 0][nb];
        const float4 a1 = *(const float4*)&At[kq * 4 + 1][nb];
        const float4 a2 = *(const float4*)&At[kq * 4 + 2][nb];
        const float4 a3 = *(const float4*)&At[kq * 4 + 3][nb];
        #pragma unroll
        for (int c = 0; c < 8; ++c) {
            const float4 w = *(const float4*)(wp + (size_t)c * HD + kq * 4);
            acc[c].x += w.x * a0.x + w.y * a1.x + w.z * a2.x + w.w * a3.x;
            acc[c].y += w.x * a0.y + w.y * a1.y + w.z * a2.y + w.w * a3.y;
            acc[c].z += w.x * a0.z + w.y * a1.z + w.z * a2.z + w.w * a3.z;
            acc[c].w += w.x * a0.w + w.y * a1.w + w.z * a2.w + w.w * a3.w;
        }
    }

    {
        const size_t pb = (size_t)kc * NN + n0 + ngt * 4;
        #pragma unroll
        for (int c = 0; c < 8; ++c) {
            P[(pb + 0) * 128 + colbase + c] = acc[c].x;
            P[(pb + 1) * 128 + colbase + c] = acc[c].y;
            P[(pb + 2) * 128 + colbase + c] = acc[c].z;
            P[(pb + 3) * 128 + colbase + c] = acc[c].w;
        }
    }
}

// ---------------------------------------------------------------------------
// K3b: t = relu(LN(sum_kc P)); u = t@Wo2^T + A@W1^T; z = relu(LN(u));
//      out = relu(z@W2^T + A).  Block 128 thr, 8 nodes; grid 256.
// ---------------------------------------------------------------------------
__global__ __launch_bounds__(128) void epilogue_kernel(
    const float* __restrict__ P, const float* __restrict__ agents,
    const float* __restrict__ go, const float* __restrict__ bo,
    const float* __restrict__ Wo2, const float* __restrict__ W1,
    const float* __restrict__ gn, const float* __restrict__ bn,
    const float* __restrict__ W2, float* __restrict__ out)
{
    __shared__ float As[8][132];
    __shared__ float ts[8][132];
    __shared__ float zs[8][132];
    __shared__ float red[2][8][2];
    const int tid = threadIdx.x;
    const int cg = tid >> 3, n = tid & 7;
    const int n0 = blockIdx.x * 8;
    const int colbase = cg * 8;

    {
        const float4* src = (const float4*)(agents + (size_t)n0 * 128);
        #pragma unroll
        for (int r = 0; r < 2; ++r) {
            const int idx = tid + r * 128;
            const int row = idx >> 5, c4 = idx & 31;
            *(float4*)&As[row][c4 * 4] = src[idx];
        }
    }

    // t-acc = sum of KC K-partials
    float acc[8] = {0.f, 0.f, 0.f, 0.f, 0.f, 0.f, 0.f, 0.f};
    {
        #pragma unroll
        for (int kcc = 0; kcc < KC; ++kcc) {
            const float* p = P + ((size_t)kcc * NN + n0 + n) * 128 + colbase;
            const float4 a = *(const float4*)p;
            const float4 b = *(const float4*)(p + 4);
            acc[0] += a.x; acc[1] += a.y; acc[2] += a.z; acc[3] += a.w;
            acc[4] += b.x; acc[5] += b.y; acc[6] += b.z; acc[7] += b.w;
        }
    }

    // LN(128) -> ts = relu(LN*go+bo)
    {
        float s = 0.f, q = 0.f;
        #pragma unroll
        for (int jj = 0; jj < 8; ++jj) { s += acc[jj]; q += acc[jj] * acc[jj]; }
        #pragma unroll
        for (int mask = 8; mask <= 32; mask <<= 1) {
            s += __shfl_xor(s, mask); q += __shfl_xor(q, mask);
        }
        if ((tid & 63) < 8) { red[tid >> 6][tid & 7][0] = s; red[tid >> 6][tid & 7][1] = q; }
        __syncthreads();
        const float st = red[0][n][0] + red[1][n][0];
        const float qt = red[0][n][1] + red[1][n][1];
        const float mu = st * (1.f / 128.f);
        const float var = qt * (1.f / 128.f) - mu * mu;
        const float rs = rsqrtf(var + 1e-5f);
        float t[8];
        #pragma unroll
        for (int jj = 0; jj < 8; ++jj) {
            const int c = colbase + jj;
            t[jj] = fmaxf((acc[jj] - mu) * rs * go[c] + bo[c], 0.f);
        }
        *(float4*)&ts[n][colbase]     = make_float4(t[0], t[1], t[2], t[3]);
        *(float4*)&ts[n][colbase + 4] = make_float4(t[4], t[5], t[6], t[7]);
    }
    __syncthreads();

    // u = t@Wo2^T + A@W1^T
    float acc2[8] = {0.f, 0.f, 0.f, 0.f, 0.f, 0.f, 0.f, 0.f};
    for (int k4 = 0; k4 < 32; ++k4) {
        const float4 t4 = *(const float4*)&ts[n][k4 * 4];
        const float4 a4 = *(const float4*)&As[n][k4 * 4];
        #pragma unroll
        for (int jj = 0; jj < 8; ++jj) {
            const float4 w2 = *(const float4*)(Wo2 + (size_t)(colbase + jj) * 128 + k4 * 4);
            const float4 w1 = *(const float4*)(W1 + (size_t)(colbase + jj) * 128 + k4 * 4);
            acc2[jj] += dot4(t4, w2) + dot4(a4, w1);
        }
    }

    // LN(128) -> zs = relu(LN*gn+bn)
    {
        float s = 0.f, q = 0.f;
        #pragma unroll
        for (int jj = 0; jj < 8; ++jj) { s += acc2[jj]; q += acc2[jj] * acc2[jj]; }
        #pragma unroll
        for (int mask = 8; mask <= 32; mask <<= 1) {
            s += __shfl_xor(s, mask); q += __shfl_xor(q, mask);
        }
        __syncthreads();
        if ((tid & 63) < 8) { red[tid >> 6][tid & 7][0] = s; red[tid >> 6][tid & 7][1] = q; }
        __syncthreads();
        const float st = red[0][n][0] + red[1][n][0];
        const float qt = red[0][n][1] + red[1][n][1];
        const float mu = st * (1.f / 128.f);
        const float var = qt * (1.f / 128.f) - mu * mu;
        const float rs = rsqrtf(var + 1e-5f);
        float z[8];
        #pragma unroll
        for (int jj = 0; jj < 8; ++jj) {
            const int c = colbase + jj;
            z[jj] = fmaxf((acc2[jj] - mu) * rs * gn[c] + bn[c], 0.f);
        }
        *(float4*)&zs[n][colbase]     = make_float4(z[0], z[1], z[2], z[3]);
        *(float4*)&zs[n][colbase + 4] = make_float4(z[4], z[5], z[6], z[7]);
    }
    __syncthreads();

    // out = relu(z@W2^T + A)
    float acc3[8] = {0.f, 0.f, 0.f, 0.f, 0.f, 0.f, 0.f, 0.f};
    for (int k4 = 0; k4 < 32; ++k4) {
        const float4 z4 = *(const float4*)&zs[n][k4 * 4];
        #pragma unroll
        for (int jj = 0; jj < 8; ++jj) {
            const float4 w = *(const float4*)(W2 + (size_t)(colbase + jj) * 128 + k4 * 4);
            acc3[jj] += dot4(z4, w);
        }
    }
    const float4 ar0 = *(const float4*)&As[n][colbase];
    const float4 ar1 = *(const float4*)&As[n][colbase + 4];
    float* op = out + ((size_t)n0 + n) * 128 + colbase;
    *(float4*)op = make_float4(fmaxf(acc3[0] + ar0.x, 0.f), fmaxf(acc3[1] + ar0.y, 0.f),
                               fmaxf(acc3[2] + ar0.z, 0.f), fmaxf(acc3[3] + ar0.w, 0.f));
    *(float4*)(op + 4) = make_float4(fmaxf(acc3[4] + ar1.x, 0.f), fmaxf(acc3[5] + ar1.y, 0.f),
                                     fmaxf(acc3[6] + ar1.z, 0.f), fmaxf(acc3[7] + ar1.w, 0.f));
}

// ---------------------------------------------------------------------------
extern "C" void kernel_launch(void* const* d_in, const int* in_sizes, int n_in,
                              void* d_out, int out_size, void* d_ws, size_t ws_size,
                              hipStream_t stream) {
    (void)in_sizes; (void)n_in; (void)out_size; (void)ws_size;
    const float* agents = (const float*)d_in[0];
    const float* Wq  = (const float*)d_in[3];
    const float* gq  = (const float*)d_in[4];
    const float* bq  = (const float*)d_in[5];
    const float* Wk  = (const float*)d_in[6];
    const float* gk  = (const float*)d_in[7];
    const float* bk  = (const float*)d_in[8];
    const float* Wv  = (const float*)d_in[9];
    const float* gv  = (const float*)d_in[10];
    const float* bv  = (const float*)d_in[11];
    const float* Wo1 = (const float*)d_in[12];
    const float* go  = (const float*)d_in[13];
    const float* bo  = (const float*)d_in[14];
    const float* Wo2 = (const float*)d_in[15];
    const float* W1  = (const float*)d_in[16];
    const float* gn  = (const float*)d_in[17];
    const float* bn  = (const float*)d_in[18];
    const float* W2  = (const float*)d_in[19];
    float* out = (float*)d_out;

    float* ws = (float*)d_ws;
    float* R  = ws;                                   // 3*2048*768
    float* ps = R + (size_t)3 * NN * HD;              // 3*2048*12
    float* O  = ps + (size_t)3 * NN * 12;             // 2048*768
    float* P  = R;                                    // alias: R dead after attn

    proj_gemm_kernel<<<dim3(32, 18), 256, 0, stream>>>(agents, Wq, Wk, Wv, R, ps);
    attn_kernel<<<dim3(NB, HH), 256, 0, stream>>>(R, ps, gq, bq, gk, bk, gv, bv, O);
    wo1_gemm_kernel<<<dim3(32, KC), 256, 0, stream>>>(O, Wo1, P);
    epilogue_kernel<<<NN / 8, 128, 0, stream>>>(P, agents, go, bo, Wo2, W1, gn, bn, W2, out);
}

// Round 6
// 173.480 us; speedup vs baseline: 1.4593x; 1.4593x over previous
//
#include <hip/hip_runtime.h>
#include <math.h>

#define NN 2048      // nodes
#define HH 6         // heads
#define HD 768       // H*D
#define NA 32        // agents/scene
#define NB 64        // scenes
#define KC 3         // wo1 K-split chunks (256 each)

typedef __bf16 bf16x8 __attribute__((ext_vector_type(8)));
typedef float  f32x4  __attribute__((ext_vector_type(4)));

__device__ __forceinline__ float dot4(float4 a, float4 b) {
    return a.x * b.x + a.y * b.y + a.z * b.z + a.w * b.w;
}

// split f into bf16 hi + bf16 lo (truncation; hi+lo ~ 2^-17 relative)
__device__ __forceinline__ void split2(float f, ushort& h, ushort& l) {
    const uint u = __float_as_uint(f);
    h = (ushort)(u >> 16);
    const float hf = __uint_as_float((uint)h << 16);
    l = (ushort)(__float_as_uint(f - hf) >> 16);
}

// ---------------------------------------------------------------------------
// K0: split agents / Wq / Wk / Wv / Wo1 into bf16 hi+lo pairs.
// grid (256, 5) x 256 thr, 1 float4 per thread.
// ---------------------------------------------------------------------------
__global__ __launch_bounds__(256) void split_kernel(
    const float* __restrict__ agents, const float* __restrict__ Wq,
    const float* __restrict__ Wk, const float* __restrict__ Wv,
    const float* __restrict__ Wo1,
    ushort* __restrict__ Ahi, ushort* __restrict__ Alo,
    ushort* __restrict__ Whi, ushort* __restrict__ Wlo,
    ushort* __restrict__ W1hi, ushort* __restrict__ W1lo)
{
    const int y = blockIdx.y;
    const float* src;
    ushort *dh, *dl;
    int n4;
    if (y == 0)      { src = agents; dh = Ahi;  dl = Alo;  n4 = NN * 128 / 4; }
    else if (y == 4) { src = Wo1;    dh = W1hi; dl = W1lo; n4 = 128 * HD / 4; }
    else {
        src = (y == 1) ? Wq : (y == 2) ? Wk : Wv;
        dh = Whi + (size_t)(y - 1) * 768 * 128;
        dl = Wlo + (size_t)(y - 1) * 768 * 128;
        n4 = 768 * 128 / 4;
    }
    const int i = blockIdx.x * 256 + threadIdx.x;
    if (i < n4) {
        const float4 v = ((const float4*)src)[i];
        ushort4 h, l;
        split2(v.x, h.x, l.x);
        split2(v.y, h.y, l.y);
        split2(v.z, h.z, l.z);
        split2(v.w, h.w, l.w);
        ((ushort4*)dh)[i] = h;
        ((ushort4*)dl)[i] = l;
    }
}

// ---------------------------------------------------------------------------
// K1: R[node][m*768+c] = agents @ W^T via bf16x3 MFMA (fp32-class accuracy).
// Block 256 thr = 4 waves; wave = 16 rows x 64 cols strip; block 64r x 64c.
// Grid (32, 36). No LDS; W L1/L2 resident. R layout [3][2048][768].
// ---------------------------------------------------------------------------
__global__ __launch_bounds__(256) void proj_mfma_kernel(
    const ushort* __restrict__ Ahi, const ushort* __restrict__ Alo,
    const ushort* __restrict__ Whi, const ushort* __restrict__ Wlo,
    float* __restrict__ R)
{
    const int tid = threadIdx.x;
    const int wave = tid >> 6, lane = tid & 63;
    const int row0 = blockIdx.x * 64 + wave * 16;
    const int cb0  = blockIdx.y * 64;
    const int lrow = lane & 15, kq = lane >> 4;   // kq = 0..3
    const int koff = kq * 8;

    const ushort* ah = Ahi + (size_t)(row0 + lrow) * 128 + koff;
    const ushort* al = Alo + (size_t)(row0 + lrow) * 128 + koff;

    f32x4 acc[4];
    #pragma unroll
    for (int ct = 0; ct < 4; ++ct)
        #pragma unroll
        for (int j = 0; j < 4; ++j) acc[ct][j] = 0.f;

    #pragma unroll
    for (int kt = 0; kt < 4; ++kt) {
        const bf16x8 avh = *(const bf16x8*)(ah + kt * 32);
        const bf16x8 avl = *(const bf16x8*)(al + kt * 32);
        #pragma unroll
        for (int ct = 0; ct < 4; ++ct) {
            const size_t wof = (size_t)(cb0 + ct * 16 + lrow) * 128 + koff + kt * 32;
            const bf16x8 bvh = *(const bf16x8*)(Whi + wof);
            const bf16x8 bvl = *(const bf16x8*)(Wlo + wof);
            acc[ct] = __builtin_amdgcn_mfma_f32_16x16x32_bf16(avh, bvh, acc[ct], 0, 0, 0);
            acc[ct] = __builtin_amdgcn_mfma_f32_16x16x32_bf16(avh, bvl, acc[ct], 0, 0, 0);
            acc[ct] = __builtin_amdgcn_mfma_f32_16x16x32_bf16(avl, bvh, acc[ct], 0, 0, 0);
        }
    }

    // D: col = lane&15, row = (lane>>4)*4 + j  (verified mapping)
    #pragma unroll
    for (int ct = 0; ct < 4; ++ct) {
        const int colg = cb0 + ct * 16;
        const int m = colg / 768;
        const int c = colg - m * 768 + lrow;
        float* rp = R + ((size_t)m * NN + row0 + kq * 4) * HD + c;
        #pragma unroll
        for (int j = 0; j < 4; ++j)
            rp[(size_t)j * HD] = acc[ct][j];
    }
}

// ---------------------------------------------------------------------------
// K2: full-row LN stats: ps[m*NN+node] = {sum, sumsq} over 768.
// Block 256 = 4 waves, 1 row per wave. Grid 1536.
// ---------------------------------------------------------------------------
__global__ __launch_bounds__(256) void stats_kernel(
    const float* __restrict__ R, float* __restrict__ ps)
{
    const int wave = threadIdx.x >> 6, lane = threadIdx.x & 63;
    const int rr = blockIdx.x * 4 + wave;       // 0..6143
    const float4* rp = (const float4*)(R + (size_t)rr * HD);
    float s = 0.f, q = 0.f;
    #pragma unroll
    for (int r = 0; r < 3; ++r) {
        const float4 v = rp[lane + r * 64];
        s += v.x + v.y + v.z + v.w;
        q += v.x * v.x + v.y * v.y + v.z * v.z + v.w * v.w;
    }
    #pragma unroll
    for (int mask = 32; mask >= 1; mask >>= 1) {
        s += __shfl_xor(s, mask);
        q += __shfl_xor(q, mask);
    }
    if (lane == 0) { ps[(size_t)rr * 2] = s; ps[(size_t)rr * 2 + 1] = q; }
}

// ---------------------------------------------------------------------------
// K3: per-(scene, head) attention; LN (q,k) / LN+relu (v) applied during
// staging; O written as bf16 hi/lo pair for the MFMA wo1.
// ---------------------------------------------------------------------------
__global__ __launch_bounds__(256) void attn_kernel(
    const float* __restrict__ R, const float* __restrict__ ps,
    const float* __restrict__ gq, const float* __restrict__ bq,
    const float* __restrict__ gk, const float* __restrict__ bk,
    const float* __restrict__ gv, const float* __restrict__ bv,
    ushort* __restrict__ Ohi, ushort* __restrict__ Olo)
{
    __shared__ float Qs[32][132];
    __shared__ float Ks[32][132];
    __shared__ float Vs[32][132];
    __shared__ float Ss[32][33];
    __shared__ float stat_s[3][32][2];
    const int tid = threadIdx.x;
    const int scene = blockIdx.x, h = blockIdx.y;

    if (tid < 96) {
        const int m = tid / 32, row = tid & 31;
        const float* p = ps + ((size_t)m * NN + scene * 32 + row) * 2;
        const float mu  = p[0] * (1.f / 768.f);
        const float var = p[1] * (1.f / 768.f) - mu * mu;
        stat_s[m][row][0] = mu;
        stat_s[m][row][1] = rsqrtf(var + 1e-5f);
    }
    __syncthreads();

    for (int m = 0; m < 3; ++m) {
        const float* Rm = R + (size_t)m * NN * HD;
        const float* g = (m == 0) ? gq : (m == 1) ? gk : gv;
        const float* b = (m == 0) ? bq : (m == 1) ? bk : bv;
        float* dst = (m == 0) ? &Qs[0][0] : (m == 1) ? &Ks[0][0] : &Vs[0][0];
        #pragma unroll
        for (int r = 0; r < 4; ++r) {
            const int idx = tid + r * 256;
            const int row = idx >> 5, c4 = idx & 31;
            const float4 x = *(const float4*)(Rm + ((size_t)scene * 32 + row) * HD + h * 128 + c4 * 4);
            const float mu = stat_s[m][row][0], rs = stat_s[m][row][1];
            const float4 gg = *(const float4*)(g + h * 128 + c4 * 4);
            const float4 bb = *(const float4*)(b + h * 128 + c4 * 4);
            float4 y;
            y.x = (x.x - mu) * rs * gg.x + bb.x;
            y.y = (x.y - mu) * rs * gg.y + bb.y;
            y.z = (x.z - mu) * rs * gg.z + bb.z;
            y.w = (x.w - mu) * rs * gg.w + bb.w;
            if (m == 2) {
                y.x = fmaxf(y.x, 0.f); y.y = fmaxf(y.y, 0.f);
                y.z = fmaxf(y.z, 0.f); y.w = fmaxf(y.w, 0.f);
            }
            *(float4*)(dst + row * 132 + c4 * 4) = y;
        }
    }
    __syncthreads();

    {
        const int ti = tid >> 4, tj = tid & 15;
        float a00 = 0.f, a01 = 0.f, a10 = 0.f, a11 = 0.f;
        #pragma unroll 4
        for (int k4 = 0; k4 < 32; ++k4) {
            const float4 q0 = *(const float4*)&Qs[2 * ti][k4 * 4];
            const float4 q1 = *(const float4*)&Qs[2 * ti + 1][k4 * 4];
            const float4 k0 = *(const float4*)&Ks[2 * tj][k4 * 4];
            const float4 k1 = *(const float4*)&Ks[2 * tj + 1][k4 * 4];
            a00 += dot4(q0, k0); a01 += dot4(q0, k1);
            a10 += dot4(q1, k0); a11 += dot4(q1, k1);
        }
        const float scale = 0.08838834764831845f;  // 1/sqrt(128)
        Ss[2 * ti][2 * tj]         = a00 * scale;
        Ss[2 * ti][2 * tj + 1]     = a01 * scale;
        Ss[2 * ti + 1][2 * tj]     = a10 * scale;
        Ss[2 * ti + 1][2 * tj + 1] = a11 * scale;
    }
    __syncthreads();

    {
        const int g = tid >> 5, l = tid & 31;
        #pragma unroll
        for (int ib = 0; ib < 4; ++ib) {
            const int i = g + ib * 8;
            const float sv = Ss[i][l];
            float mx = sv;
            #pragma unroll
            for (int mask = 16; mask >= 1; mask >>= 1)
                mx = fmaxf(mx, __shfl_xor(mx, mask));
            const float p = __expf(sv - mx);
            float sum = p;
            #pragma unroll
            for (int mask = 16; mask >= 1; mask >>= 1)
                sum += __shfl_xor(sum, mask);
            Ss[i][l] = p / sum;
        }
    }
    __syncthreads();

    {
        const int i = tid >> 3, dg = tid & 7;
        float o[4][4] = {};
        for (int j = 0; j < 32; ++j) {
            const float p = Ss[i][j];
            #pragma unroll
            for (int r = 0; r < 4; ++r) {
                const float4 v4 = *(const float4*)&Vs[j][dg * 4 + 32 * r];
                o[r][0] += p * v4.x; o[r][1] += p * v4.y;
                o[r][2] += p * v4.z; o[r][3] += p * v4.w;
            }
        }
        const size_t base = ((size_t)scene * 32 + i) * HD + h * 128;
        #pragma unroll
        for (int r = 0; r < 4; ++r) {
            ushort4 hs, ls;
            split2(o[r][0], hs.x, ls.x);
            split2(o[r][1], hs.y, ls.y);
            split2(o[r][2], hs.z, ls.z);
            split2(o[r][3], hs.w, ls.w);
            *(ushort4*)(Ohi + base + dg * 4 + 32 * r) = hs;
            *(ushort4*)(Olo + base + dg * 4 + 32 * r) = ls;
        }
    }
}

// ---------------------------------------------------------------------------
// K4: P[ks] = O[:, ks*256:+256] @ Wo1[:, same]^T via bf16x3 MFMA.
// Wave = one 16x16 tile over 8 k-tiles; block 4 waves (64 rows).
// Grid (32, 8, 3). P layout [3][2048][128].
// ---------------------------------------------------------------------------
__global__ __launch_bounds__(256) void wo1_mfma_kernel(
    const ushort* __restrict__ Ohi, const ushort* __restrict__ Olo,
    const ushort* __restrict__ W1hi, const ushort* __restrict__ W1lo,
    float* __restrict__ P)
{
    const int tid = threadIdx.x;
    const int wave = tid >> 6, lane = tid & 63;
    const int row0 = blockIdx.x * 64 + wave * 16;
    const int col0 = blockIdx.y * 16;
    const int kb   = blockIdx.z * 256;
    const int lrow = lane & 15, kq = lane >> 4;
    const int koff = kq * 8;

    const ushort* ah = Ohi  + (size_t)(row0 + lrow) * HD + kb + koff;
    const ushort* al = Olo  + (size_t)(row0 + lrow) * HD + kb + koff;
    const ushort* bh = W1hi + (size_t)(col0 + lrow) * HD + kb + koff;
    const ushort* bl = W1lo + (size_t)(col0 + lrow) * HD + kb + koff;

    f32x4 acc;
    #pragma unroll
    for (int j = 0; j < 4; ++j) acc[j] = 0.f;

    #pragma unroll
    for (int kt = 0; kt < 8; ++kt) {
        const bf16x8 avh = *(const bf16x8*)(ah + kt * 32);
        const bf16x8 avl = *(const bf16x8*)(al + kt * 32);
        const bf16x8 bvh = *(const bf16x8*)(bh + kt * 32);
        const bf16x8 bvl = *(const bf16x8*)(bl + kt * 32);
        acc = __builtin_amdgcn_mfma_f32_16x16x32_bf16(avh, bvh, acc, 0, 0, 0);
        acc = __builtin_amdgcn_mfma_f32_16x16x32_bf16(avh, bvl, acc, 0, 0, 0);
        acc = __builtin_amdgcn_mfma_f32_16x16x32_bf16(avl, bvh, acc, 0, 0, 0);
    }

    float* pp = P + ((size_t)blockIdx.z * NN + row0 + kq * 4) * 128 + col0 + lrow;
    #pragma unroll
    for (int j = 0; j < 4; ++j)
        pp[(size_t)j * 128] = acc[j];
}

// ---------------------------------------------------------------------------
// K5: t = relu(LN(sum_ks P)); u = t@Wo2^T + A@W1^T; z = relu(LN(u));
//     out = relu(z@W2^T + A).  Block 128 thr, 8 nodes; grid 256.
// ---------------------------------------------------------------------------
__global__ __launch_bounds__(128) void epilogue_kernel(
    const float* __restrict__ P, const float* __restrict__ agents,
    const float* __restrict__ go, const float* __restrict__ bo,
    const float* __restrict__ Wo2, const float* __restrict__ W1,
    const float* __restrict__ gn, const float* __restrict__ bn,
    const float* __restrict__ W2, float* __restrict__ out)
{
    __shared__ float As[8][132];
    __shared__ float ts[8][132];
    __shared__ float zs[8][132];
    __shared__ float red[2][8][2];
    const int tid = threadIdx.x;
    const int cg = tid >> 3, n = tid & 7;
    const int n0 = blockIdx.x * 8;
    const int colbase = cg * 8;

    {
        const float4* src = (const float4*)(agents + (size_t)n0 * 128);
        #pragma unroll
        for (int r = 0; r < 2; ++r) {
            const int idx = tid + r * 128;
            const int row = idx >> 5, c4 = idx & 31;
            *(float4*)&As[row][c4 * 4] = src[idx];
        }
    }

    float acc[8] = {0.f, 0.f, 0.f, 0.f, 0.f, 0.f, 0.f, 0.f};
    {
        #pragma unroll
        for (int kcc = 0; kcc < KC; ++kcc) {
            const float* p = P + ((size_t)kcc * NN + n0 + n) * 128 + colbase;
            const float4 a = *(const float4*)p;
            const float4 b = *(const float4*)(p + 4);
            acc[0] += a.x; acc[1] += a.y; acc[2] += a.z; acc[3] += a.w;
            acc[4] += b.x; acc[5] += b.y; acc[6] += b.z; acc[7] += b.w;
        }
    }

    // LN(128) -> ts = relu(LN*go+bo)
    {
        float s = 0.f, q = 0.f;
        #pragma unroll
        for (int jj = 0; jj < 8; ++jj) { s += acc[jj]; q += acc[jj] * acc[jj]; }
        #pragma unroll
        for (int mask = 8; mask <= 32; mask <<= 1) {
            s += __shfl_xor(s, mask); q += __shfl_xor(q, mask);
        }
        if ((tid & 63) < 8) { red[tid >> 6][tid & 7][0] = s; red[tid >> 6][tid & 7][1] = q; }
        __syncthreads();
        const float st = red[0][n][0] + red[1][n][0];
        const float qt = red[0][n][1] + red[1][n][1];
        const float mu = st * (1.f / 128.f);
        const float var = qt * (1.f / 128.f) - mu * mu;
        const float rs = rsqrtf(var + 1e-5f);
        float t[8];
        #pragma unroll
        for (int jj = 0; jj < 8; ++jj) {
            const int c = colbase + jj;
            t[jj] = fmaxf((acc[jj] - mu) * rs * go[c] + bo[c], 0.f);
        }
        *(float4*)&ts[n][colbase]     = make_float4(t[0], t[1], t[2], t[3]);
        *(float4*)&ts[n][colbase + 4] = make_float4(t[4], t[5], t[6], t[7]);
    }
    __syncthreads();

    // u = t@Wo2^T + A@W1^T
    float acc2[8] = {0.f, 0.f, 0.f, 0.f, 0.f, 0.f, 0.f, 0.f};
    for (int k4 = 0; k4 < 32; ++k4) {
        const float4 t4 = *(const float4*)&ts[n][k4 * 4];
        const float4 a4 = *(const float4*)&As[n][k4 * 4];
        #pragma unroll
        for (int jj = 0; jj < 8; ++jj) {
            const float4 w2 = *(const float4*)(Wo2 + (size_t)(colbase + jj) * 128 + k4 * 4);
            const float4 w1 = *(const float4*)(W1 + (size_t)(colbase + jj) * 128 + k4 * 4);
            acc2[jj] += dot4(t4, w2) + dot4(a4, w1);
        }
    }

    // LN(128) -> zs = relu(LN*gn+bn)
    {
        float s = 0.f, q = 0.f;
        #pragma unroll
        for (int jj = 0; jj < 8; ++jj) { s += acc2[jj]; q += acc2[jj] * acc2[jj]; }
        #pragma unroll
        for (int mask = 8; mask <= 32; mask <<= 1) {
            s += __shfl_xor(s, mask); q += __shfl_xor(q, mask);
        }
        __syncthreads();
        if ((tid & 63) < 8) { red[tid >> 6][tid & 7][0] = s; red[tid >> 6][tid & 7][1] = q; }
        __syncthreads();
        const float st = red[0][n][0] + red[1][n][0];
        const float qt = red[0][n][1] + red[1][n][1];
        const float mu = st * (1.f / 128.f);
        const float var = qt * (1.f / 128.f) - mu * mu;
        const float rs = rsqrtf(var + 1e-5f);
        float z[8];
        #pragma unroll
        for (int jj = 0; jj < 8; ++jj) {
            const int c = colbase + jj;
            z[jj] = fmaxf((acc2[jj] - mu) * rs * gn[c] + bn[c], 0.f);
        }
        *(float4*)&zs[n][colbase]     = make_float4(z[0], z[1], z[2], z[3]);
        *(float4*)&zs[n][colbase + 4] = make_float4(z[4], z[5], z[6], z[7]);
    }
    __syncthreads();

    // out = relu(z@W2^T + A)
    float acc3[8] = {0.f, 0.f, 0.f, 0.f, 0.f, 0.f, 0.f, 0.f};
    for (int k4 = 0; k4 < 32; ++k4) {
        const float4 z4 = *(const float4*)&zs[n][k4 * 4];
        #pragma unroll
        for (int jj = 0; jj < 8; ++jj) {
            const float4 w = *(const float4*)(W2 + (size_t)(colbase + jj) * 128 + k4 * 4);
            acc3[jj] += dot4(z4, w);
        }
    }
    const float4 ar0 = *(const float4*)&As[n][colbase];
    const float4 ar1 = *(const float4*)&As[n][colbase + 4];
    float* op = out + ((size_t)n0 + n) * 128 + colbase;
    *(float4*)op = make_float4(fmaxf(acc3[0] + ar0.x, 0.f), fmaxf(acc3[1] + ar0.y, 0.f),
                               fmaxf(acc3[2] + ar0.z, 0.f), fmaxf(acc3[3] + ar0.w, 0.f));
    *(float4*)(op + 4) = make_float4(fmaxf(acc3[4] + ar1.x, 0.f), fmaxf(acc3[5] + ar1.y, 0.f),
                                     fmaxf(acc3[6] + ar1.z, 0.f), fmaxf(acc3[7] + ar1.w, 0.f));
}

// ---------------------------------------------------------------------------
extern "C" void kernel_launch(void* const* d_in, const int* in_sizes, int n_in,
                              void* d_out, int out_size, void* d_ws, size_t ws_size,
                              hipStream_t stream) {
    (void)in_sizes; (void)n_in; (void)out_size; (void)ws_size;
    const float* agents = (const float*)d_in[0];
    const float* Wq  = (const float*)d_in[3];
    const float* gq  = (const float*)d_in[4];
    const float* bq  = (const float*)d_in[5];
    const float* Wk  = (const float*)d_in[6];
    const float* gk  = (const float*)d_in[7];
    const float* bk  = (const float*)d_in[8];
    const float* Wv  = (const float*)d_in[9];
    const float* gv  = (const float*)d_in[10];
    const float* bv  = (const float*)d_in[11];
    const float* Wo1 = (const float*)d_in[12];
    const float* go  = (const float*)d_in[13];
    const float* bo  = (const float*)d_in[14];
    const float* Wo2 = (const float*)d_in[15];
    const float* W1  = (const float*)d_in[16];
    const float* gn  = (const float*)d_in[17];
    const float* bn  = (const float*)d_in[18];
    const float* W2  = (const float*)d_in[19];
    float* out = (float*)d_out;

    float* ws = (float*)d_ws;
    float* R  = ws;                                   // 3*2048*768 fp32
    float* P  = R;                                    // alias: R dead after attn
    float* ps = R + (size_t)3 * NN * HD;              // 6144*2 fp32
    ushort* u = (ushort*)(ps + (size_t)2 * 3 * NN);   // 16B-aligned bf16 zone
    ushort* Ohi  = u;  u += (size_t)NN * HD;
    ushort* Olo  = u;  u += (size_t)NN * HD;
    ushort* Ahi  = u;  u += (size_t)NN * 128;
    ushort* Alo  = u;  u += (size_t)NN * 128;
    ushort* Whi  = u;  u += (size_t)3 * 768 * 128;
    ushort* Wlo  = u;  u += (size_t)3 * 768 * 128;
    ushort* W1hi = u;  u += (size_t)128 * HD;
    ushort* W1lo = u;  u += (size_t)128 * HD;

    split_kernel<<<dim3(256, 5), 256, 0, stream>>>(agents, Wq, Wk, Wv, Wo1,
                                                   Ahi, Alo, Whi, Wlo, W1hi, W1lo);
    proj_mfma_kernel<<<dim3(32, 36), 256, 0, stream>>>(Ahi, Alo, Whi, Wlo, R);
    stats_kernel<<<1536, 256, 0, stream>>>(R, ps);
    attn_kernel<<<dim3(NB, HH), 256, 0, stream>>>(R, ps, gq, bq, gk, bk, gv, bv, Ohi, Olo);
    wo1_mfma_kernel<<<dim3(32, 8, 3), 256, 0, stream>>>(Ohi, Olo, W1hi, W1lo, P);
    epilogue_kernel<<<NN / 8, 128, 0, stream>>>(P, agents, go, bo, Wo2, W1, gn, bn, W2, out);
}

// Round 8
// 170.831 us; speedup vs baseline: 1.4819x; 1.0155x over previous
//
#include <hip/hip_runtime.h>
#include <math.h>

#define NN 2048      // nodes
#define HH 6         // heads
#define HD 768       // H*D
#define NA 32        // agents/scene
#define NB 64        // scenes

typedef __bf16 bf16x8 __attribute__((ext_vector_type(8)));
typedef float  f32x4  __attribute__((ext_vector_type(4)));

// split f into bf16 hi + bf16 lo (truncation; hi+lo ~ 2^-17 relative)
__device__ __forceinline__ void split2(float f, ushort& h, ushort& l) {
    const uint u = __float_as_uint(f);
    h = (ushort)(u >> 16);
    const float hf = __uint_as_float((uint)h << 16);
    l = (ushort)(__float_as_uint(f - hf) >> 16);
}

__device__ __forceinline__ bf16x8 pack8(const ushort* s) {
    uint4 u;
    u.x = (uint)s[0] | ((uint)s[1] << 16);
    u.y = (uint)s[2] | ((uint)s[3] << 16);
    u.z = (uint)s[4] | ((uint)s[5] << 16);
    u.w = (uint)s[6] | ((uint)s[7] << 16);
    return *(bf16x8*)&u;
}

// load 8 fp32, apply LN (gamma/beta), split to bf16 hi/lo fragments
__device__ __forceinline__ void ln8_split(
    const float* __restrict__ x, float mu, float rs,
    const float* __restrict__ g, const float* __restrict__ b,
    bf16x8& hi, bf16x8& lo)
{
    const float4 x0 = *(const float4*)x;
    const float4 x1 = *(const float4*)(x + 4);
    const float4 g0 = *(const float4*)g;
    const float4 g1 = *(const float4*)(g + 4);
    const float4 b0 = *(const float4*)b;
    const float4 b1 = *(const float4*)(b + 4);
    ushort hh[8], ll[8];
    float v;
    v = (x0.x - mu) * rs * g0.x + b0.x; split2(v, hh[0], ll[0]);
    v = (x0.y - mu) * rs * g0.y + b0.y; split2(v, hh[1], ll[1]);
    v = (x0.z - mu) * rs * g0.z + b0.z; split2(v, hh[2], ll[2]);
    v = (x0.w - mu) * rs * g0.w + b0.w; split2(v, hh[3], ll[3]);
    v = (x1.x - mu) * rs * g1.x + b1.x; split2(v, hh[4], ll[4]);
    v = (x1.y - mu) * rs * g1.y + b1.y; split2(v, hh[5], ll[5]);
    v = (x1.z - mu) * rs * g1.z + b1.z; split2(v, hh[6], ll[6]);
    v = (x1.w - mu) * rs * g1.w + b1.w; split2(v, hh[7], ll[7]);
    hi = pack8(hh); lo = pack8(ll);
}

// ---------------------------------------------------------------------------
// K0: split agents / Wq / Wk / Wv / Wo1 / Wo2 / W1 / W2 into bf16 hi+lo.
// grid (256, 8) x 256 thr, 1 float4 per thread.
// ---------------------------------------------------------------------------
__global__ __launch_bounds__(256) void split_kernel(
    const float* __restrict__ agents, const float* __restrict__ Wq,
    const float* __restrict__ Wk, const float* __restrict__ Wv,
    const float* __restrict__ Wo1, const float* __restrict__ Wo2,
    const float* __restrict__ W1, const float* __restrict__ W2,
    ushort* __restrict__ Ahi, ushort* __restrict__ Alo,
    ushort* __restrict__ Whi, ushort* __restrict__ Wlo,
    ushort* __restrict__ Wo1hi, ushort* __restrict__ Wo1lo,
    ushort* __restrict__ Wo2hi, ushort* __restrict__ Wo2lo,
    ushort* __restrict__ W1hi, ushort* __restrict__ W1lo,
    ushort* __restrict__ W2hi, ushort* __restrict__ W2lo)
{
    const int y = blockIdx.y;
    const float* src;
    ushort *dh, *dl;
    int n4;
    switch (y) {
        case 0:  src = agents; dh = Ahi;   dl = Alo;   n4 = NN * 128 / 4;  break;
        case 1:  src = Wq;  dh = Whi;                dl = Wlo;                n4 = 768*128/4; break;
        case 2:  src = Wk;  dh = Whi + 768*128;      dl = Wlo + 768*128;      n4 = 768*128/4; break;
        case 3:  src = Wv;  dh = Whi + 2*768*128;    dl = Wlo + 2*768*128;    n4 = 768*128/4; break;
        case 4:  src = Wo1; dh = Wo1hi; dl = Wo1lo;  n4 = 128 * HD / 4;  break;
        case 5:  src = Wo2; dh = Wo2hi; dl = Wo2lo;  n4 = 128 * 128 / 4; break;
        case 6:  src = W1;  dh = W1hi;  dl = W1lo;   n4 = 128 * 128 / 4; break;
        default: src = W2;  dh = W2hi;  dl = W2lo;   n4 = 128 * 128 / 4; break;
    }
    const int i = blockIdx.x * 256 + threadIdx.x;
    if (i < n4) {
        const float4 v = ((const float4*)src)[i];
        ushort4 h, l;
        split2(v.x, h.x, l.x);
        split2(v.y, h.y, l.y);
        split2(v.z, h.z, l.z);
        split2(v.w, h.w, l.w);
        ((ushort4*)dh)[i] = h;
        ((ushort4*)dl)[i] = l;
    }
}

// ---------------------------------------------------------------------------
// K1: R[m][node][c] = agents @ Wm^T via bf16x3 MFMA. Grid (32, 36), 256 thr.
// ---------------------------------------------------------------------------
__global__ __launch_bounds__(256) void proj_mfma_kernel(
    const ushort* __restrict__ Ahi, const ushort* __restrict__ Alo,
    const ushort* __restrict__ Whi, const ushort* __restrict__ Wlo,
    float* __restrict__ R)
{
    const int tid = threadIdx.x;
    const int wave = tid >> 6, lane = tid & 63;
    const int row0 = blockIdx.x * 64 + wave * 16;
    const int cb0  = blockIdx.y * 64;
    const int lrow = lane & 15, kq = lane >> 4;
    const int koff = kq * 8;

    const ushort* ah = Ahi + (size_t)(row0 + lrow) * 128 + koff;
    const ushort* al = Alo + (size_t)(row0 + lrow) * 128 + koff;

    f32x4 acc[4];
    #pragma unroll
    for (int ct = 0; ct < 4; ++ct)
        #pragma unroll
        for (int j = 0; j < 4; ++j) acc[ct][j] = 0.f;

    #pragma unroll
    for (int kt = 0; kt < 4; ++kt) {
        const bf16x8 avh = *(const bf16x8*)(ah + kt * 32);
        const bf16x8 avl = *(const bf16x8*)(al + kt * 32);
        #pragma unroll
        for (int ct = 0; ct < 4; ++ct) {
            const size_t wof = (size_t)(cb0 + ct * 16 + lrow) * 128 + koff + kt * 32;
            const bf16x8 bvh = *(const bf16x8*)(Whi + wof);
            const bf16x8 bvl = *(const bf16x8*)(Wlo + wof);
            acc[ct] = __builtin_amdgcn_mfma_f32_16x16x32_bf16(avh, bvh, acc[ct], 0, 0, 0);
            acc[ct] = __builtin_amdgcn_mfma_f32_16x16x32_bf16(avh, bvl, acc[ct], 0, 0, 0);
            acc[ct] = __builtin_amdgcn_mfma_f32_16x16x32_bf16(avl, bvh, acc[ct], 0, 0, 0);
        }
    }

    #pragma unroll
    for (int ct = 0; ct < 4; ++ct) {
        const int colg = cb0 + ct * 16;
        const int m = colg / 768;
        const int c = colg - m * 768 + lrow;
        float* rp = R + ((size_t)m * NN + row0 + kq * 4) * HD + c;
        #pragma unroll
        for (int j = 0; j < 4; ++j)
            rp[(size_t)j * HD] = acc[ct][j];
    }
}

// ---------------------------------------------------------------------------
// K2: full-row LN stats: ps[m*NN+node] = {sum, sumsq} over 768. Grid 1536.
// ---------------------------------------------------------------------------
__global__ __launch_bounds__(256) void stats_kernel(
    const float* __restrict__ R, float* __restrict__ ps)
{
    const int wave = threadIdx.x >> 6, lane = threadIdx.x & 63;
    const int rr = blockIdx.x * 4 + wave;
    const float4* rp = (const float4*)(R + (size_t)rr * HD);
    float s = 0.f, q = 0.f;
    #pragma unroll
    for (int r = 0; r < 3; ++r) {
        const float4 v = rp[lane + r * 64];
        s += v.x + v.y + v.z + v.w;
        q += v.x * v.x + v.y * v.y + v.z * v.z + v.w * v.w;
    }
    #pragma unroll
    for (int mask = 32; mask >= 1; mask >>= 1) {
        s += __shfl_xor(s, mask);
        q += __shfl_xor(q, mask);
    }
    if (lane == 0) { ps[(size_t)rr * 2] = s; ps[(size_t)rr * 2 + 1] = q; }
}

// ---------------------------------------------------------------------------
// K3: attention via bf16x3 MFMA. One wave per (scene, head, 16-query tile).
// Grid (64, 6, 2) x 64 thr. LN fused into fragment builds; softmax in regs;
// P transposed via small LDS bounce; O written pre-split bf16 hi/lo.
// ---------------------------------------------------------------------------
__global__ __launch_bounds__(64) void attn_mfma_kernel(
    const float* __restrict__ R, const float* __restrict__ ps,
    const float* __restrict__ gq, const float* __restrict__ bq,
    const float* __restrict__ gk, const float* __restrict__ bk,
    const float* __restrict__ gv, const float* __restrict__ bv,
    ushort* __restrict__ Ohi, ushort* __restrict__ Olo)
{
    __shared__ ushort phi[16][40];   // pitch 40 u16 = 80B (16B-aligned rows)
    __shared__ ushort plo[16][40];
    const int lane = threadIdx.x;
    const int lrow = lane & 15, kq = lane >> 4;
    const int scene = blockIdx.x, h = blockIdx.y, rt = blockIdx.z;
    const int brow = scene * 32;

    const float* Rq = R;
    const float* Rk = R + (size_t)NN * HD;
    const float* Rv = R + (size_t)2 * NN * HD;

    // LN stats (full-768 rows)
    const int qrow = brow + rt * 16 + lrow;
    const float2 sq_ = *(const float2*)(ps + (size_t)qrow * 2);
    const float muq = sq_.x * (1.f / 768.f);
    const float rsq = rsqrtf(sq_.y * (1.f / 768.f) - muq * muq + 1e-5f);

    float muk[2], rsk[2];
    #pragma unroll
    for (int ct = 0; ct < 2; ++ct) {
        const int krow = brow + ct * 16 + lrow;
        const float2 sk_ = *(const float2*)(ps + (size_t)(NN + krow) * 2);
        muk[ct] = sk_.x * (1.f / 768.f);
        rsk[ct] = rsqrtf(sk_.y * (1.f / 768.f) - muk[ct] * muk[ct] + 1e-5f);
    }
    float muv[8], rsv[8];
    #pragma unroll
    for (int j = 0; j < 8; ++j) {
        const int vrow = brow + kq * 8 + j;
        const float2 sv_ = *(const float2*)(ps + (size_t)(2 * NN + vrow) * 2);
        muv[j] = sv_.x * (1.f / 768.f);
        rsv[j] = rsqrtf(sv_.y * (1.f / 768.f) - muv[j] * muv[j] + 1e-5f);
    }

    // S = Q K^T (16 queries x 32 keys), LN fused into fragment builds
    f32x4 s[2];
    #pragma unroll
    for (int ct = 0; ct < 2; ++ct)
        #pragma unroll
        for (int j = 0; j < 4; ++j) s[ct][j] = 0.f;

    #pragma unroll
    for (int kt = 0; kt < 4; ++kt) {
        const int c0 = h * 128 + kt * 32 + kq * 8;
        bf16x8 qh, ql;
        ln8_split(Rq + (size_t)qrow * HD + c0, muq, rsq, gq + c0, bq + c0, qh, ql);
        #pragma unroll
        for (int ct = 0; ct < 2; ++ct) {
            bf16x8 kh, kl;
            ln8_split(Rk + (size_t)(brow + ct * 16 + lrow) * HD + c0, muk[ct], rsk[ct],
                      gk + c0, bk + c0, kh, kl);
            s[ct] = __builtin_amdgcn_mfma_f32_16x16x32_bf16(qh, kh, s[ct], 0, 0, 0);
            s[ct] = __builtin_amdgcn_mfma_f32_16x16x32_bf16(qh, kl, s[ct], 0, 0, 0);
            s[ct] = __builtin_amdgcn_mfma_f32_16x16x32_bf16(ql, kh, s[ct], 0, 0, 0);
        }
    }

    // row softmax over 32 keys: row = kq*4+j, cols spread over lrow x 2 ct
    const float scl = 0.08838834764831845f;  // 1/sqrt(128)
    float p0[4], p1[4];
    #pragma unroll
    for (int j = 0; j < 4; ++j) {
        const float a = s[0][j] * scl, b = s[1][j] * scl;
        float m = fmaxf(a, b);
        #pragma unroll
        for (int msk = 1; msk <= 8; msk <<= 1) m = fmaxf(m, __shfl_xor(m, msk));
        const float ea = __expf(a - m), eb = __expf(b - m);
        float su = ea + eb;
        #pragma unroll
        for (int msk = 1; msk <= 8; msk <<= 1) su += __shfl_xor(su, msk);
        const float inv = 1.f / su;
        p0[j] = ea * inv;
        p1[j] = eb * inv;
    }

    // transpose P to A-frag layout via LDS
    #pragma unroll
    for (int j = 0; j < 4; ++j) {
        ushort hh, ll;
        split2(p0[j], hh, ll);
        phi[kq * 4 + j][lrow] = hh;
        plo[kq * 4 + j][lrow] = ll;
        split2(p1[j], hh, ll);
        phi[kq * 4 + j][16 + lrow] = hh;
        plo[kq * 4 + j][16 + lrow] = ll;
    }
    __syncthreads();
    const bf16x8 pah = *(const bf16x8*)&phi[lrow][kq * 8];
    const bf16x8 pal = *(const bf16x8*)&plo[lrow][kq * 8];

    // O = P V, streaming over 8 d-tiles; LN+relu on V fused into B-frag build
    #pragma unroll
    for (int dt = 0; dt < 8; ++dt) {
        const int d = h * 128 + dt * 16 + lrow;
        const float gvd = gv[d], bvd = bv[d];
        ushort vh[8], vl[8];
        #pragma unroll
        for (int j = 0; j < 8; ++j) {
            const float x = Rv[(size_t)(brow + kq * 8 + j) * HD + d];
            const float v = fmaxf((x - muv[j]) * rsv[j] * gvd + bvd, 0.f);
            split2(v, vh[j], vl[j]);
        }
        const bf16x8 bh = pack8(vh), bl = pack8(vl);
        f32x4 o;
        #pragma unroll
        for (int j = 0; j < 4; ++j) o[j] = 0.f;
        o = __builtin_amdgcn_mfma_f32_16x16x32_bf16(pah, bh, o, 0, 0, 0);
        o = __builtin_amdgcn_mfma_f32_16x16x32_bf16(pah, bl, o, 0, 0, 0);
        o = __builtin_amdgcn_mfma_f32_16x16x32_bf16(pal, bh, o, 0, 0, 0);
        #pragma unroll
        for (int j = 0; j < 4; ++j) {
            const size_t oo = (size_t)(brow + rt * 16 + kq * 4 + j) * HD + d;
            ushort hh, ll;
            split2(o[j], hh, ll);
            Ohi[oo] = hh;
            Olo[oo] = ll;
        }
    }
}

// ---------------------------------------------------------------------------
// K4: P[kc] = O[:, kc*256:+256] @ Wo1[:, same]^T via bf16x3 MFMA.
// Grid (32, 8, 3) x 256 thr. P layout [3][2048][128].
// ---------------------------------------------------------------------------
__global__ __launch_bounds__(256) void wo1_mfma_kernel(
    const ushort* __restrict__ Ohi, const ushort* __restrict__ Olo,
    const ushort* __restrict__ Wo1hi, const ushort* __restrict__ Wo1lo,
    float* __restrict__ P)
{
    const int tid = threadIdx.x;
    const int wave = tid >> 6, lane = tid & 63;
    const int row0 = blockIdx.x * 64 + wave * 16;
    const int col0 = blockIdx.y * 16;
    const int kb   = blockIdx.z * 256;
    const int lrow = lane & 15, kq = lane >> 4;
    const int koff = kq * 8;

    const ushort* ah = Ohi   + (size_t)(row0 + lrow) * HD + kb + koff;
    const ushort* al = Olo   + (size_t)(row0 + lrow) * HD + kb + koff;
    const ushort* bh = Wo1hi + (size_t)(col0 + lrow) * HD + kb + koff;
    const ushort* bl = Wo1lo + (size_t)(col0 + lrow) * HD + kb + koff;

    f32x4 acc;
    #pragma unroll
    for (int j = 0; j < 4; ++j) acc[j] = 0.f;

    #pragma unroll
    for (int kt = 0; kt < 8; ++kt) {
        const bf16x8 avh = *(const bf16x8*)(ah + kt * 32);
        const bf16x8 avl = *(const bf16x8*)(al + kt * 32);
        const bf16x8 bvh = *(const bf16x8*)(bh + kt * 32);
        const bf16x8 bvl = *(const bf16x8*)(bl + kt * 32);
        acc = __builtin_amdgcn_mfma_f32_16x16x32_bf16(avh, bvh, acc, 0, 0, 0);
        acc = __builtin_amdgcn_mfma_f32_16x16x32_bf16(avh, bvl, acc, 0, 0, 0);
        acc = __builtin_amdgcn_mfma_f32_16x16x32_bf16(avl, bvh, acc, 0, 0, 0);
    }

    float* pp = P + ((size_t)blockIdx.z * NN + row0 + kq * 4) * 128 + col0 + lrow;
    #pragma unroll
    for (int j = 0; j < 4; ++j)
        pp[(size_t)j * 128] = acc[j];
}

// ---------------------------------------------------------------------------
// K5: fused epilogue via bf16x3 MFMA. One wave per 16 nodes, grid 128.
//  t = relu(LN(P0+P1+P2)) built directly in A-frag layout (no transpose);
//  u = t@Wo2^T + A@W1^T (192 MFMA); z = relu(LN(u)) -> LDS transpose;
//  out = relu(z@W2^T + A) (96 MFMA).
// ---------------------------------------------------------------------------
__global__ __launch_bounds__(64) void epilogue_mfma_kernel(
    const float* __restrict__ P,
    const ushort* __restrict__ Ahi, const ushort* __restrict__ Alo,
    const float* __restrict__ agents,
    const float* __restrict__ go, const float* __restrict__ bo,
    const ushort* __restrict__ Wo2hi, const ushort* __restrict__ Wo2lo,
    const ushort* __restrict__ W1hi, const ushort* __restrict__ W1lo,
    const float* __restrict__ gn, const float* __restrict__ bn,
    const ushort* __restrict__ W2hi, const ushort* __restrict__ W2lo,
    float* __restrict__ out)
{
    __shared__ float zb[16][132];
    const int lane = threadIdx.x;
    const int lrow = lane & 15, kq = lane >> 4;
    const int n0 = blockIdx.x * 16;
    const int nodeA = n0 + lrow;

    // ---- t = relu(LN(sum P)), A-frag layout: row=lrow, k = kt*32+kq*8+j ----
    float tv[4][8];
    float s = 0.f, q = 0.f;
    #pragma unroll
    for (int kt = 0; kt < 4; ++kt) {
        const int c0 = kt * 32 + kq * 8;
        const float* pp0 = P + (size_t)nodeA * 128 + c0;
        const float* pp1 = pp0 + (size_t)NN * 128;
        const float* pp2 = pp1 + (size_t)NN * 128;
        #pragma unroll
        for (int hf = 0; hf < 2; ++hf) {
            const float4 a = *(const float4*)(pp0 + hf * 4);
            const float4 b = *(const float4*)(pp1 + hf * 4);
            const float4 c = *(const float4*)(pp2 + hf * 4);
            tv[kt][hf * 4 + 0] = a.x + b.x + c.x;
            tv[kt][hf * 4 + 1] = a.y + b.y + c.y;
            tv[kt][hf * 4 + 2] = a.z + b.z + c.z;
            tv[kt][hf * 4 + 3] = a.w + b.w + c.w;
        }
        #pragma unroll
        for (int j = 0; j < 8; ++j) { s += tv[kt][j]; q += tv[kt][j] * tv[kt][j]; }
    }
    s += __shfl_xor(s, 16); s += __shfl_xor(s, 32);
    q += __shfl_xor(q, 16); q += __shfl_xor(q, 32);
    const float mu = s * (1.f / 128.f);
    const float rs = rsqrtf(q * (1.f / 128.f) - mu * mu + 1e-5f);

    bf16x8 th[4], tl[4], ah[4], al[4];
    #pragma unroll
    for (int kt = 0; kt < 4; ++kt) {
        const int c0 = kt * 32 + kq * 8;
        const float4 g0 = *(const float4*)(go + c0);
        const float4 g1 = *(const float4*)(go + c0 + 4);
        const float4 b0 = *(const float4*)(bo + c0);
        const float4 b1 = *(const float4*)(bo + c0 + 4);
        const float gg[8] = {g0.x, g0.y, g0.z, g0.w, g1.x, g1.y, g1.z, g1.w};
        const float bb[8] = {b0.x, b0.y, b0.z, b0.w, b1.x, b1.y, b1.z, b1.w};
        ushort hh[8], ll[8];
        #pragma unroll
        for (int j = 0; j < 8; ++j) {
            const float v = fmaxf((tv[kt][j] - mu) * rs * gg[j] + bb[j], 0.f);
            split2(v, hh[j], ll[j]);
        }
        th[kt] = pack8(hh); tl[kt] = pack8(ll);
        ah[kt] = *(const bf16x8*)(Ahi + (size_t)nodeA * 128 + c0);
        al[kt] = *(const bf16x8*)(Alo + (size_t)nodeA * 128 + c0);
    }

    // ---- u = t@Wo2^T + A@W1^T ----
    f32x4 u[8];
    #pragma unroll
    for (int ct = 0; ct < 8; ++ct)
        #pragma unroll
        for (int j = 0; j < 4; ++j) u[ct][j] = 0.f;

    #pragma unroll
    for (int ct = 0; ct < 8; ++ct) {
        const size_t wb = (size_t)(ct * 16 + lrow) * 128;
        #pragma unroll
        for (int kt = 0; kt < 4; ++kt) {
            const int c0 = kt * 32 + kq * 8;
            const bf16x8 wh = *(const bf16x8*)(Wo2hi + wb + c0);
            const bf16x8 wl = *(const bf16x8*)(Wo2lo + wb + c0);
            const bf16x8 vh = *(const bf16x8*)(W1hi + wb + c0);
            const bf16x8 vl = *(const bf16x8*)(W1lo + wb + c0);
            u[ct] = __builtin_amdgcn_mfma_f32_16x16x32_bf16(th[kt], wh, u[ct], 0, 0, 0);
            u[ct] = __builtin_amdgcn_mfma_f32_16x16x32_bf16(th[kt], wl, u[ct], 0, 0, 0);
            u[ct] = __builtin_amdgcn_mfma_f32_16x16x32_bf16(tl[kt], wh, u[ct], 0, 0, 0);
            u[ct] = __builtin_amdgcn_mfma_f32_16x16x32_bf16(ah[kt], vh, u[ct], 0, 0, 0);
            u[ct] = __builtin_amdgcn_mfma_f32_16x16x32_bf16(ah[kt], vl, u[ct], 0, 0, 0);
            u[ct] = __builtin_amdgcn_mfma_f32_16x16x32_bf16(al[kt], vh, u[ct], 0, 0, 0);
        }
    }

    // ---- z = relu(LN(u)) -> LDS (C-layout rows = kq*4+j) ----
    float gnc[8], bnc[8];
    #pragma unroll
    for (int ct = 0; ct < 8; ++ct) {
        gnc[ct] = gn[ct * 16 + lrow];
        bnc[ct] = bn[ct * 16 + lrow];
    }
    #pragma unroll
    for (int j = 0; j < 4; ++j) {
        float s2 = 0.f, q2 = 0.f;
        #pragma unroll
        for (int ct = 0; ct < 8; ++ct) { const float v = u[ct][j]; s2 += v; q2 += v * v; }
        #pragma unroll
        for (int msk = 1; msk <= 8; msk <<= 1) {
            s2 += __shfl_xor(s2, msk);
            q2 += __shfl_xor(q2, msk);
        }
        const float mu2 = s2 * (1.f / 128.f);
        const float rs2 = rsqrtf(q2 * (1.f / 128.f) - mu2 * mu2 + 1e-5f);
        #pragma unroll
        for (int ct = 0; ct < 8; ++ct)
            zb[kq * 4 + j][ct * 16 + lrow] =
                fmaxf((u[ct][j] - mu2) * rs2 * gnc[ct] + bnc[ct], 0.f);
    }
    __syncthreads();

    // ---- out = relu(z@W2^T + A) ----
    bf16x8 zh[4], zl[4];
    #pragma unroll
    for (int kt = 0; kt < 4; ++kt) {
        const int c0 = kt * 32 + kq * 8;
        const float4 z0 = *(const float4*)&zb[lrow][c0];
        const float4 z1 = *(const float4*)&zb[lrow][c0 + 4];
        const float zz[8] = {z0.x, z0.y, z0.z, z0.w, z1.x, z1.y, z1.z, z1.w};
        ushort hh[8], ll[8];
        #pragma unroll
        for (int j = 0; j < 8; ++j) split2(zz[j], hh[j], ll[j]);
        zh[kt] = pack8(hh); zl[kt] = pack8(ll);
    }
    #pragma unroll
    for (int ct = 0; ct < 8; ++ct) {
        f32x4 o;
        #pragma unroll
        for (int j = 0; j < 4; ++j) o[j] = 0.f;
        const size_t wb = (size_t)(ct * 16 + lrow) * 128;
        #pragma unroll
        for (int kt = 0; kt < 4; ++kt) {
            const int c0 = kt * 32 + kq * 8;
            const bf16x8 wh = *(const bf16x8*)(W2hi + wb + c0);
            const bf16x8 wl = *(const bf16x8*)(W2lo + wb + c0);
            o = __builtin_amdgcn_mfma_f32_16x16x32_bf16(zh[kt], wh, o, 0, 0, 0);
            o = __builtin_amdgcn_mfma_f32_16x16x32_bf16(zh[kt], wl, o, 0, 0, 0);
            o = __builtin_amdgcn_mfma_f32_16x16x32_bf16(zl[kt], wh, o, 0, 0, 0);
        }
        #pragma unroll
        for (int j = 0; j < 4; ++j) {
            const size_t oo = (size_t)(n0 + kq * 4 + j) * 128 + ct * 16 + lrow;
            out[oo] = fmaxf(o[j] + agents[oo], 0.f);
        }
    }
}

// ---------------------------------------------------------------------------
extern "C" void kernel_launch(void* const* d_in, const int* in_sizes, int n_in,
                              void* d_out, int out_size, void* d_ws, size_t ws_size,
                              hipStream_t stream) {
    (void)in_sizes; (void)n_in; (void)out_size; (void)ws_size;
    const float* agents = (const float*)d_in[0];
    const float* Wq  = (const float*)d_in[3];
    const float* gq  = (const float*)d_in[4];
    const float* bq  = (const float*)d_in[5];
    const float* Wk  = (const float*)d_in[6];
    const float* gk  = (const float*)d_in[7];
    const float* bk  = (const float*)d_in[8];
    const float* Wv  = (const float*)d_in[9];
    const float* gv  = (const float*)d_in[10];
    const float* bv  = (const float*)d_in[11];
    const float* Wo1 = (const float*)d_in[12];
    const float* go  = (const float*)d_in[13];
    const float* bo  = (const float*)d_in[14];
    const float* Wo2 = (const float*)d_in[15];
    const float* W1  = (const float*)d_in[16];
    const float* gn  = (const float*)d_in[17];
    const float* bn  = (const float*)d_in[18];
    const float* W2  = (const float*)d_in[19];
    float* out = (float*)d_out;

    float* ws = (float*)d_ws;
    float* R  = ws;                                   // 3*2048*768 fp32
    float* Pp = R;                                    // alias: R dead after attn
    float* ps = R + (size_t)3 * NN * HD;              // 6144*2 fp32
    ushort* u = (ushort*)(ps + (size_t)2 * 3 * NN);   // 16B-aligned bf16 zone
    ushort* Ohi   = u;  u += (size_t)NN * HD;
    ushort* Olo   = u;  u += (size_t)NN * HD;
    ushort* Ahi   = u;  u += (size_t)NN * 128;
    ushort* Alo   = u;  u += (size_t)NN * 128;
    ushort* Whi   = u;  u += (size_t)3 * 768 * 128;
    ushort* Wlo   = u;  u += (size_t)3 * 768 * 128;
    ushort* Wo1hi = u;  u += (size_t)128 * HD;
    ushort* Wo1lo = u;  u += (size_t)128 * HD;
    ushort* Wo2hi = u;  u += (size_t)128 * 128;
    ushort* Wo2lo = u;  u += (size_t)128 * 128;
    ushort* W1hi  = u;  u += (size_t)128 * 128;
    ushort* W1lo  = u;  u += (size_t)128 * 128;
    ushort* W2hi  = u;  u += (size_t)128 * 128;
    ushort* W2lo  = u;  u += (size_t)128 * 128;

    split_kernel<<<dim3(256, 8), 256, 0, stream>>>(
        agents, Wq, Wk, Wv, Wo1, Wo2, W1, W2,
        Ahi, Alo, Whi, Wlo, Wo1hi, Wo1lo, Wo2hi, Wo2lo, W1hi, W1lo, W2hi, W2lo);
    proj_mfma_kernel<<<dim3(32, 36), 256, 0, stream>>>(Ahi, Alo, Whi, Wlo, R);
    stats_kernel<<<1536, 256, 0, stream>>>(R, ps);
    attn_mfma_kernel<<<dim3(64, 6, 2), 64, 0, stream>>>(R, ps, gq, bq, gk, bk, gv, bv, Ohi, Olo);
    wo1_mfma_kernel<<<dim3(32, 8, 3), 256, 0, stream>>>(Ohi, Olo, Wo1hi, Wo1lo, Pp);
    epilogue_mfma_kernel<<<128, 64, 0, stream>>>(Pp, Ahi, Alo, agents, go, bo,
                                                 Wo2hi, Wo2lo, W1hi, W1lo, gn, bn,
                                                 W2hi, W2lo, out);
}

// Round 10
// 160.440 us; speedup vs baseline: 1.5779x; 1.0648x over previous
//
#include <hip/hip_runtime.h>
#include <math.h>

#define NN 2048      // nodes
#define HH 6         // heads
#define HD 768       // H*D
#define NA 32        // agents/scene
#define NB 64        // scenes

typedef __bf16 bf16x8 __attribute__((ext_vector_type(8)));
typedef float  f32x4  __attribute__((ext_vector_type(4)));

// split f into bf16 hi + bf16 lo (truncation; hi+lo ~ 2^-17 relative)
__device__ __forceinline__ void split2(float f, ushort& h, ushort& l) {
    const uint u = __float_as_uint(f);
    h = (ushort)(u >> 16);
    const float hf = __uint_as_float((uint)h << 16);
    l = (ushort)(__float_as_uint(f - hf) >> 16);
}

__device__ __forceinline__ bf16x8 pack8(const ushort* s) {
    uint4 u;
    u.x = (uint)s[0] | ((uint)s[1] << 16);
    u.y = (uint)s[2] | ((uint)s[3] << 16);
    u.z = (uint)s[4] | ((uint)s[5] << 16);
    u.w = (uint)s[6] | ((uint)s[7] << 16);
    return *(bf16x8*)&u;
}

// load 8 fp32, apply LN (gamma/beta), split to bf16 hi/lo fragments
__device__ __forceinline__ void ln8_split(
    const float* __restrict__ x, float mu, float rs,
    const float* __restrict__ g, const float* __restrict__ b,
    bf16x8& hi, bf16x8& lo)
{
    const float4 x0 = *(const float4*)x;
    const float4 x1 = *(const float4*)(x + 4);
    const float4 g0 = *(const float4*)g;
    const float4 g1 = *(const float4*)(g + 4);
    const float4 b0 = *(const float4*)b;
    const float4 b1 = *(const float4*)(b + 4);
    ushort hh[8], ll[8];
    float v;
    v = (x0.x - mu) * rs * g0.x + b0.x; split2(v, hh[0], ll[0]);
    v = (x0.y - mu) * rs * g0.y + b0.y; split2(v, hh[1], ll[1]);
    v = (x0.z - mu) * rs * g0.z + b0.z; split2(v, hh[2], ll[2]);
    v = (x0.w - mu) * rs * g0.w + b0.w; split2(v, hh[3], ll[3]);
    v = (x1.x - mu) * rs * g1.x + b1.x; split2(v, hh[4], ll[4]);
    v = (x1.y - mu) * rs * g1.y + b1.y; split2(v, hh[5], ll[5]);
    v = (x1.z - mu) * rs * g1.z + b1.z; split2(v, hh[6], ll[6]);
    v = (x1.w - mu) * rs * g1.w + b1.w; split2(v, hh[7], ll[7]);
    hi = pack8(hh); lo = pack8(ll);
}

// ---------------------------------------------------------------------------
// K0: split agents / Wq / Wk / Wv / Wo1 / Wo2 / W1 / W2 into bf16 hi+lo.
// ---------------------------------------------------------------------------
__global__ __launch_bounds__(256) void split_kernel(
    const float* __restrict__ agents, const float* __restrict__ Wq,
    const float* __restrict__ Wk, const float* __restrict__ Wv,
    const float* __restrict__ Wo1, const float* __restrict__ Wo2,
    const float* __restrict__ W1, const float* __restrict__ W2,
    ushort* __restrict__ Ahi, ushort* __restrict__ Alo,
    ushort* __restrict__ Whi, ushort* __restrict__ Wlo,
    ushort* __restrict__ Wo1hi, ushort* __restrict__ Wo1lo,
    ushort* __restrict__ Wo2hi, ushort* __restrict__ Wo2lo,
    ushort* __restrict__ W1hi, ushort* __restrict__ W1lo,
    ushort* __restrict__ W2hi, ushort* __restrict__ W2lo)
{
    const int y = blockIdx.y;
    const float* src;
    ushort *dh, *dl;
    int n4;
    switch (y) {
        case 0:  src = agents; dh = Ahi;   dl = Alo;   n4 = NN * 128 / 4;  break;
        case 1:  src = Wq;  dh = Whi;                dl = Wlo;                n4 = 768*128/4; break;
        case 2:  src = Wk;  dh = Whi + 768*128;      dl = Wlo + 768*128;      n4 = 768*128/4; break;
        case 3:  src = Wv;  dh = Whi + 2*768*128;    dl = Wlo + 2*768*128;    n4 = 768*128/4; break;
        case 4:  src = Wo1; dh = Wo1hi; dl = Wo1lo;  n4 = 128 * HD / 4;  break;
        case 5:  src = Wo2; dh = Wo2hi; dl = Wo2lo;  n4 = 128 * 128 / 4; break;
        case 6:  src = W1;  dh = W1hi;  dl = W1lo;   n4 = 128 * 128 / 4; break;
        default: src = W2;  dh = W2hi;  dl = W2lo;   n4 = 128 * 128 / 4; break;
    }
    const int i = blockIdx.x * 256 + threadIdx.x;
    if (i < n4) {
        const float4 v = ((const float4*)src)[i];
        ushort4 h, l;
        split2(v.x, h.x, l.x);
        split2(v.y, h.y, l.y);
        split2(v.z, h.z, l.z);
        split2(v.w, h.w, l.w);
        ((ushort4*)dh)[i] = h;
        ((ushort4*)dl)[i] = l;
    }
}

// ---------------------------------------------------------------------------
// K1: R[m][node][c] = agents @ Wm^T via bf16x3 MFMA + per-64-col LN partials.
// Grid (32, 36) x 256 thr. ps layout [3][NN][12][2] (partial {sum, sumsq}).
// ---------------------------------------------------------------------------
__global__ __launch_bounds__(256) void proj_mfma_kernel(
    const ushort* __restrict__ Ahi, const ushort* __restrict__ Alo,
    const ushort* __restrict__ Whi, const ushort* __restrict__ Wlo,
    float* __restrict__ R, float* __restrict__ ps)
{
    const int tid = threadIdx.x;
    const int wave = tid >> 6, lane = tid & 63;
    const int row0 = blockIdx.x * 64 + wave * 16;
    const int cb0  = blockIdx.y * 64;
    const int m0   = blockIdx.y / 12, pb = blockIdx.y % 12;
    const int lrow = lane & 15, kq = lane >> 4;
    const int koff = kq * 8;

    const ushort* ah = Ahi + (size_t)(row0 + lrow) * 128 + koff;
    const ushort* al = Alo + (size_t)(row0 + lrow) * 128 + koff;

    f32x4 acc[4];
    #pragma unroll
    for (int ct = 0; ct < 4; ++ct)
        #pragma unroll
        for (int j = 0; j < 4; ++j) acc[ct][j] = 0.f;

    #pragma unroll
    for (int kt = 0; kt < 4; ++kt) {
        const bf16x8 avh = *(const bf16x8*)(ah + kt * 32);
        const bf16x8 avl = *(const bf16x8*)(al + kt * 32);
        #pragma unroll
        for (int ct = 0; ct < 4; ++ct) {
            const size_t wof = (size_t)(cb0 + ct * 16 + lrow) * 128 + koff + kt * 32;
            const bf16x8 bvh = *(const bf16x8*)(Whi + wof);
            const bf16x8 bvl = *(const bf16x8*)(Wlo + wof);
            acc[ct] = __builtin_amdgcn_mfma_f32_16x16x32_bf16(avh, bvh, acc[ct], 0, 0, 0);
            acc[ct] = __builtin_amdgcn_mfma_f32_16x16x32_bf16(avh, bvl, acc[ct], 0, 0, 0);
            acc[ct] = __builtin_amdgcn_mfma_f32_16x16x32_bf16(avl, bvh, acc[ct], 0, 0, 0);
        }
    }

    // D: col = lane&15, row = (lane>>4)*4 + j
    const int cloc = cb0 - m0 * 768;   // col base within matrix m0
    #pragma unroll
    for (int ct = 0; ct < 4; ++ct) {
        const int c = cloc + ct * 16 + lrow;
        float* rp = R + ((size_t)m0 * NN + row0 + kq * 4) * HD + c;
        #pragma unroll
        for (int j = 0; j < 4; ++j)
            rp[(size_t)j * HD] = acc[ct][j];
    }

    // per-row partial LN stats over this block's 64 cols
    #pragma unroll
    for (int j = 0; j < 4; ++j) {
        float sj = acc[0][j] + acc[1][j] + acc[2][j] + acc[3][j];
        float qj = acc[0][j] * acc[0][j] + acc[1][j] * acc[1][j]
                 + acc[2][j] * acc[2][j] + acc[3][j] * acc[3][j];
        #pragma unroll
        for (int msk = 1; msk <= 8; msk <<= 1) {
            sj += __shfl_xor(sj, msk);
            qj += __shfl_xor(qj, msk);
        }
        if (lrow == 0) {
            const size_t o = ((size_t)m0 * NN + row0 + kq * 4 + j) * 24 + pb * 2;
            ps[o]     = sj;
            ps[o + 1] = qj;
        }
    }
}

// ---------------------------------------------------------------------------
// K3: attention via bf16x3 MFMA. One wave per (scene, head, 16-query tile).
// Grid (64, 6, 2) x 64 thr. Stats combined once into LDS; LN fused into
// fragment builds; softmax in regs; P via LDS bounce; O pre-split bf16.
// ---------------------------------------------------------------------------
__global__ __launch_bounds__(64) void attn_mfma_kernel(
    const float* __restrict__ R, const float* __restrict__ ps,
    const float* __restrict__ gq, const float* __restrict__ bq,
    const float* __restrict__ gk, const float* __restrict__ bk,
    const float* __restrict__ gv, const float* __restrict__ bv,
    ushort* __restrict__ Ohi, ushort* __restrict__ Olo)
{
    __shared__ ushort phi[16][40];
    __shared__ ushort plo[16][40];
    __shared__ float stat_s[3][32][2];
    const int lane = threadIdx.x;
    const int lrow = lane & 15, kq = lane >> 4;
    const int scene = blockIdx.x, h = blockIdx.y, rt = blockIdx.z;
    const int brow = scene * 32;

    const float* Rq = R;
    const float* Rk = R + (size_t)NN * HD;
    const float* Rv = R + (size_t)2 * NN * HD;

    // combine 12 LN partials per row into LDS {mu, rstd}
    for (int i = lane; i < 96; i += 64) {
        const int m = i >> 5, row = i & 31;
        const float4* pv = (const float4*)(ps + ((size_t)m * NN + brow + row) * 24);
        float s = 0.f, q = 0.f;
        #pragma unroll
        for (int c = 0; c < 6; ++c) {
            const float4 v = pv[c];
            s += v.x + v.z;
            q += v.y + v.w;
        }
        const float mu  = s * (1.f / 768.f);
        const float var = q * (1.f / 768.f) - mu * mu;
        stat_s[m][row][0] = mu;
        stat_s[m][row][1] = rsqrtf(var + 1e-5f);
    }
    __syncthreads();

    const int qrow = brow + rt * 16 + lrow;
    const float muq = stat_s[0][rt * 16 + lrow][0];
    const float rsq = stat_s[0][rt * 16 + lrow][1];
    float muk[2], rsk[2];
    #pragma unroll
    for (int ct = 0; ct < 2; ++ct) {
        muk[ct] = stat_s[1][ct * 16 + lrow][0];
        rsk[ct] = stat_s[1][ct * 16 + lrow][1];
    }
    float muv[8], rsv[8];
    #pragma unroll
    for (int j = 0; j < 8; ++j) {
        muv[j] = stat_s[2][kq * 8 + j][0];
        rsv[j] = stat_s[2][kq * 8 + j][1];
    }

    // S = Q K^T (16 queries x 32 keys)
    f32x4 s[2];
    #pragma unroll
    for (int ct = 0; ct < 2; ++ct)
        #pragma unroll
        for (int j = 0; j < 4; ++j) s[ct][j] = 0.f;

    #pragma unroll
    for (int kt = 0; kt < 4; ++kt) {
        const int c0 = h * 128 + kt * 32 + kq * 8;
        bf16x8 qh, ql;
        ln8_split(Rq + (size_t)qrow * HD + c0, muq, rsq, gq + c0, bq + c0, qh, ql);
        #pragma unroll
        for (int ct = 0; ct < 2; ++ct) {
            bf16x8 kh, kl;
            ln8_split(Rk + (size_t)(brow + ct * 16 + lrow) * HD + c0, muk[ct], rsk[ct],
                      gk + c0, bk + c0, kh, kl);
            s[ct] = __builtin_amdgcn_mfma_f32_16x16x32_bf16(qh, kh, s[ct], 0, 0, 0);
            s[ct] = __builtin_amdgcn_mfma_f32_16x16x32_bf16(qh, kl, s[ct], 0, 0, 0);
            s[ct] = __builtin_amdgcn_mfma_f32_16x16x32_bf16(ql, kh, s[ct], 0, 0, 0);
        }
    }

    // row softmax over 32 keys (row = kq*4+j; cols spread over lrow x 2 ct)
    const float scl = 0.08838834764831845f;  // 1/sqrt(128)
    float p0[4], p1[4];
    #pragma unroll
    for (int j = 0; j < 4; ++j) {
        const float a = s[0][j] * scl, b = s[1][j] * scl;
        float m = fmaxf(a, b);
        #pragma unroll
        for (int msk = 1; msk <= 8; msk <<= 1) m = fmaxf(m, __shfl_xor(m, msk));
        const float ea = __expf(a - m), eb = __expf(b - m);
        float su = ea + eb;
        #pragma unroll
        for (int msk = 1; msk <= 8; msk <<= 1) su += __shfl_xor(su, msk);
        const float inv = 1.f / su;
        p0[j] = ea * inv;
        p1[j] = eb * inv;
    }

    // transpose P to A-frag layout via LDS
    #pragma unroll
    for (int j = 0; j < 4; ++j) {
        ushort hh, ll;
        split2(p0[j], hh, ll);
        phi[kq * 4 + j][lrow] = hh;
        plo[kq * 4 + j][lrow] = ll;
        split2(p1[j], hh, ll);
        phi[kq * 4 + j][16 + lrow] = hh;
        plo[kq * 4 + j][16 + lrow] = ll;
    }
    __syncthreads();
    const bf16x8 pah = *(const bf16x8*)&phi[lrow][kq * 8];
    const bf16x8 pal = *(const bf16x8*)&plo[lrow][kq * 8];

    // O = P V over 8 d-tiles; LN+relu on V fused into B-frag build
    #pragma unroll
    for (int dt = 0; dt < 8; ++dt) {
        const int d = h * 128 + dt * 16 + lrow;
        const float gvd = gv[d], bvd = bv[d];
        ushort vh[8], vl[8];
        #pragma unroll
        for (int j = 0; j < 8; ++j) {
            const float x = Rv[(size_t)(brow + kq * 8 + j) * HD + d];
            const float v = fmaxf((x - muv[j]) * rsv[j] * gvd + bvd, 0.f);
            split2(v, vh[j], vl[j]);
        }
        const bf16x8 bh = pack8(vh), bl = pack8(vl);
        f32x4 o;
        #pragma unroll
        for (int j = 0; j < 4; ++j) o[j] = 0.f;
        o = __builtin_amdgcn_mfma_f32_16x16x32_bf16(pah, bh, o, 0, 0, 0);
        o = __builtin_amdgcn_mfma_f32_16x16x32_bf16(pah, bl, o, 0, 0, 0);
        o = __builtin_amdgcn_mfma_f32_16x16x32_bf16(pal, bh, o, 0, 0, 0);
        #pragma unroll
        for (int j = 0; j < 4; ++j) {
            const size_t oo = (size_t)(brow + rt * 16 + kq * 4 + j) * HD + d;
            ushort hh, ll;
            split2(o[j], hh, ll);
            Ohi[oo] = hh;
            Olo[oo] = ll;
        }
    }
}

// ---------------------------------------------------------------------------
// K4: P[kc] = O[:, kc*256:+256] @ Wo1[:, same]^T via bf16x3 MFMA.
// Grid (32, 8, 3) x 256 thr. P layout [3][2048][128].
// ---------------------------------------------------------------------------
__global__ __launch_bounds__(256) void wo1_mfma_kernel(
    const ushort* __restrict__ Ohi, const ushort* __restrict__ Olo,
    const ushort* __restrict__ Wo1hi, const ushort* __restrict__ Wo1lo,
    float* __restrict__ P)
{
    const int tid = threadIdx.x;
    const int wave = tid >> 6, lane = tid & 63;
    const int row0 = blockIdx.x * 64 + wave * 16;
    const int col0 = blockIdx.y * 16;
    const int kb   = blockIdx.z * 256;
    const int lrow = lane & 15, kq = lane >> 4;
    const int koff = kq * 8;

    const ushort* ah = Ohi   + (size_t)(row0 + lrow) * HD + kb + koff;
    const ushort* al = Olo   + (size_t)(row0 + lrow) * HD + kb + koff;
    const ushort* bh = Wo1hi + (size_t)(col0 + lrow) * HD + kb + koff;
    const ushort* bl = Wo1lo + (size_t)(col0 + lrow) * HD + kb + koff;

    f32x4 acc;
    #pragma unroll
    for (int j = 0; j < 4; ++j) acc[j] = 0.f;

    #pragma unroll
    for (int kt = 0; kt < 8; ++kt) {
        const bf16x8 avh = *(const bf16x8*)(ah + kt * 32);
        const bf16x8 avl = *(const bf16x8*)(al + kt * 32);
        const bf16x8 bvh = *(const bf16x8*)(bh + kt * 32);
        const bf16x8 bvl = *(const bf16x8*)(bl + kt * 32);
        acc = __builtin_amdgcn_mfma_f32_16x16x32_bf16(avh, bvh, acc, 0, 0, 0);
        acc = __builtin_amdgcn_mfma_f32_16x16x32_bf16(avh, bvl, acc, 0, 0, 0);
        acc = __builtin_amdgcn_mfma_f32_16x16x32_bf16(avl, bvh, acc, 0, 0, 0);
    }

    float* pp = P + ((size_t)blockIdx.z * NN + row0 + kq * 4) * 128 + col0 + lrow;
    #pragma unroll
    for (int j = 0; j < 4; ++j)
        pp[(size_t)j * 128] = acc[j];
}

// ---------------------------------------------------------------------------
// K5: fused epilogue, 4 waves / block, 16 nodes / block, grid 128.
//  All waves build t/A fragments (redundant, cached); each wave computes
//  2 of the 8 output col-tiles for both GEMMs; z-LN via cross-wave LDS.
// ---------------------------------------------------------------------------
__global__ __launch_bounds__(256) void epilogue_mfma_kernel(
    const float* __restrict__ P,
    const ushort* __restrict__ Ahi, const ushort* __restrict__ Alo,
    const float* __restrict__ agents,
    const float* __restrict__ go, const float* __restrict__ bo,
    const ushort* __restrict__ Wo2hi, const ushort* __restrict__ Wo2lo,
    const ushort* __restrict__ W1hi, const ushort* __restrict__ W1lo,
    const float* __restrict__ gn, const float* __restrict__ bn,
    const ushort* __restrict__ W2hi, const ushort* __restrict__ W2lo,
    float* __restrict__ out)
{
    __shared__ float zb[16][132];
    __shared__ float red2[4][16][2];
    const int tid = threadIdx.x;
    const int wave = tid >> 6, lane = tid & 63;
    const int lrow = lane & 15, kq = lane >> 4;
    const int n0 = blockIdx.x * 16;
    const int nodeA = n0 + lrow;

    // ---- t = relu(LN(sum P)), A-frag layout (all waves, redundant) ----
    float tv[4][8];
    float s = 0.f, q = 0.f;
    #pragma unroll
    for (int kt = 0; kt < 4; ++kt) {
        const int c0 = kt * 32 + kq * 8;
        const float* pp0 = P + (size_t)nodeA * 128 + c0;
        const float* pp1 = pp0 + (size_t)NN * 128;
        const float* pp2 = pp1 + (size_t)NN * 128;
        #pragma unroll
        for (int hf = 0; hf < 2; ++hf) {
            const float4 a = *(const float4*)(pp0 + hf * 4);
            const float4 b = *(const float4*)(pp1 + hf * 4);
            const float4 c = *(const float4*)(pp2 + hf * 4);
            tv[kt][hf * 4 + 0] = a.x + b.x + c.x;
            tv[kt][hf * 4 + 1] = a.y + b.y + c.y;
            tv[kt][hf * 4 + 2] = a.z + b.z + c.z;
            tv[kt][hf * 4 + 3] = a.w + b.w + c.w;
        }
        #pragma unroll
        for (int j = 0; j < 8; ++j) { s += tv[kt][j]; q += tv[kt][j] * tv[kt][j]; }
    }
    s += __shfl_xor(s, 16); s += __shfl_xor(s, 32);
    q += __shfl_xor(q, 16); q += __shfl_xor(q, 32);
    const float mu = s * (1.f / 128.f);
    const float rs = rsqrtf(q * (1.f / 128.f) - mu * mu + 1e-5f);

    bf16x8 th[4], tl[4], ah[4], al[4];
    #pragma unroll
    for (int kt = 0; kt < 4; ++kt) {
        const int c0 = kt * 32 + kq * 8;
        const float4 g0 = *(const float4*)(go + c0);
        const float4 g1 = *(const float4*)(go + c0 + 4);
        const float4 b0 = *(const float4*)(bo + c0);
        const float4 b1 = *(const float4*)(bo + c0 + 4);
        const float gg[8] = {g0.x, g0.y, g0.z, g0.w, g1.x, g1.y, g1.z, g1.w};
        const float bb[8] = {b0.x, b0.y, b0.z, b0.w, b1.x, b1.y, b1.z, b1.w};
        ushort hh[8], ll[8];
        #pragma unroll
        for (int j = 0; j < 8; ++j) {
            const float v = fmaxf((tv[kt][j] - mu) * rs * gg[j] + bb[j], 0.f);
            split2(v, hh[j], ll[j]);
        }
        th[kt] = pack8(hh); tl[kt] = pack8(ll);
        ah[kt] = *(const bf16x8*)(Ahi + (size_t)nodeA * 128 + c0);
        al[kt] = *(const bf16x8*)(Alo + (size_t)nodeA * 128 + c0);
    }

    // ---- u = t@Wo2^T + A@W1^T  (this wave's 2 col-tiles) ----
    f32x4 u[2];
    #pragma unroll
    for (int ct2 = 0; ct2 < 2; ++ct2)
        #pragma unroll
        for (int j = 0; j < 4; ++j) u[ct2][j] = 0.f;

    #pragma unroll
    for (int ct2 = 0; ct2 < 2; ++ct2) {
        const int ct = wave * 2 + ct2;
        const size_t wb = (size_t)(ct * 16 + lrow) * 128;
        #pragma unroll
        for (int kt = 0; kt < 4; ++kt) {
            const int c0 = kt * 32 + kq * 8;
            const bf16x8 wh = *(const bf16x8*)(Wo2hi + wb + c0);
            const bf16x8 wl = *(const bf16x8*)(Wo2lo + wb + c0);
            const bf16x8 vh = *(const bf16x8*)(W1hi + wb + c0);
            const bf16x8 vl = *(const bf16x8*)(W1lo + wb + c0);
            u[ct2] = __builtin_amdgcn_mfma_f32_16x16x32_bf16(th[kt], wh, u[ct2], 0, 0, 0);
            u[ct2] = __builtin_amdgcn_mfma_f32_16x16x32_bf16(th[kt], wl, u[ct2], 0, 0, 0);
            u[ct2] = __builtin_amdgcn_mfma_f32_16x16x32_bf16(tl[kt], wh, u[ct2], 0, 0, 0);
            u[ct2] = __builtin_amdgcn_mfma_f32_16x16x32_bf16(ah[kt], vh, u[ct2], 0, 0, 0);
            u[ct2] = __builtin_amdgcn_mfma_f32_16x16x32_bf16(ah[kt], vl, u[ct2], 0, 0, 0);
            u[ct2] = __builtin_amdgcn_mfma_f32_16x16x32_bf16(al[kt], vh, u[ct2], 0, 0, 0);
        }
    }

    // ---- z = relu(LN(u)): cross-wave reduction via LDS ----
    #pragma unroll
    for (int j = 0; j < 4; ++j) {
        float s2 = u[0][j] + u[1][j];
        float q2 = u[0][j] * u[0][j] + u[1][j] * u[1][j];
        #pragma unroll
        for (int msk = 1; msk <= 8; msk <<= 1) {
            s2 += __shfl_xor(s2, msk);
            q2 += __shfl_xor(q2, msk);
        }
        if (lrow == 0) {
            red2[wave][kq * 4 + j][0] = s2;
            red2[wave][kq * 4 + j][1] = q2;
        }
    }
    __syncthreads();
    #pragma unroll
    for (int j = 0; j < 4; ++j) {
        const int row = kq * 4 + j;
        const float s2t = red2[0][row][0] + red2[1][row][0] + red2[2][row][0] + red2[3][row][0];
        const float q2t = red2[0][row][1] + red2[1][row][1] + red2[2][row][1] + red2[3][row][1];
        const float mu2 = s2t * (1.f / 128.f);
        const float rs2 = rsqrtf(q2t * (1.f / 128.f) - mu2 * mu2 + 1e-5f);
        #pragma unroll
        for (int ct2 = 0; ct2 < 2; ++ct2) {
            const int c = (wave * 2 + ct2) * 16 + lrow;
            zb[row][c] = fmaxf((u[ct2][j] - mu2) * rs2 * gn[c] + bn[c], 0.f);
        }
    }
    __syncthreads();

    // ---- out = relu(z@W2^T + A)  (this wave's 2 col-tiles) ----
    bf16x8 zh[4], zl[4];
    #pragma unroll
    for (int kt = 0; kt < 4; ++kt) {
        const int c0 = kt * 32 + kq * 8;
        const float4 z0 = *(const float4*)&zb[lrow][c0];
        const float4 z1 = *(const float4*)&zb[lrow][c0 + 4];
        const float zz[8] = {z0.x, z0.y, z0.z, z0.w, z1.x, z1.y, z1.z, z1.w};
        ushort hh[8], ll[8];
        #pragma unroll
        for (int j = 0; j < 8; ++j) split2(zz[j], hh[j], ll[j]);
        zh[kt] = pack8(hh); zl[kt] = pack8(ll);
    }
    #pragma unroll
    for (int ct2 = 0; ct2 < 2; ++ct2) {
        const int ct = wave * 2 + ct2;
        f32x4 o;
        #pragma unroll
        for (int j = 0; j < 4; ++j) o[j] = 0.f;
        const size_t wb = (size_t)(ct * 16 + lrow) * 128;
        #pragma unroll
        for (int kt = 0; kt < 4; ++kt) {
            const int c0 = kt * 32 + kq * 8;
            const bf16x8 wh = *(const bf16x8*)(W2hi + wb + c0);
            const bf16x8 wl = *(const bf16x8*)(W2lo + wb + c0);
            o = __builtin_amdgcn_mfma_f32_16x16x32_bf16(zh[kt], wh, o, 0, 0, 0);
            o = __builtin_amdgcn_mfma_f32_16x16x32_bf16(zh[kt], wl, o, 0, 0, 0);
            o = __builtin_amdgcn_mfma_f32_16x16x32_bf16(zl[kt], wh, o, 0, 0, 0);
        }
        #pragma unroll
        for (int j = 0; j < 4; ++j) {
            const size_t oo = (size_t)(n0 + kq * 4 + j) * 128 + ct * 16 + lrow;
            out[oo] = fmaxf(o[j] + agents[oo], 0.f);
        }
    }
}

// ---------------------------------------------------------------------------
extern "C" void kernel_launch(void* const* d_in, const int* in_sizes, int n_in,
                              void* d_out, int out_size, void* d_ws, size_t ws_size,
                              hipStream_t stream) {
    (void)in_sizes; (void)n_in; (void)out_size; (void)ws_size;
    const float* agents = (const float*)d_in[0];
    const float* Wq  = (const float*)d_in[3];
    const float* gq  = (const float*)d_in[4];
    const float* bq  = (const float*)d_in[5];
    const float* Wk  = (const float*)d_in[6];
    const float* gk  = (const float*)d_in[7];
    const float* bk  = (const float*)d_in[8];
    const float* Wv  = (const float*)d_in[9];
    const float* gv  = (const float*)d_in[10];
    const float* bv  = (const float*)d_in[11];
    const float* Wo1 = (const float*)d_in[12];
    const float* go  = (const float*)d_in[13];
    const float* bo  = (const float*)d_in[14];
    const float* Wo2 = (const float*)d_in[15];
    const float* W1  = (const float*)d_in[16];
    const float* gn  = (const float*)d_in[17];
    const float* bn  = (const float*)d_in[18];
    const float* W2  = (const float*)d_in[19];
    float* out = (float*)d_out;

    float* ws = (float*)d_ws;
    float* R  = ws;                                   // 3*2048*768 fp32
    float* Pp = R;                                    // alias: R dead after attn
    float* ps = R + (size_t)3 * NN * HD;              // 3*NN*24 fp32 partials
    ushort* u = (ushort*)(ps + (size_t)3 * NN * 24);  // 16B-aligned bf16 zone
    ushort* Ohi   = u;  u += (size_t)NN * HD;
    ushort* Olo   = u;  u += (size_t)NN * HD;
    ushort* Ahi   = u;  u += (size_t)NN * 128;
    ushort* Alo   = u;  u += (size_t)NN * 128;
    ushort* Whi   = u;  u += (size_t)3 * 768 * 128;
    ushort* Wlo   = u;  u += (size_t)3 * 768 * 128;
    ushort* Wo1hi = u;  u += (size_t)128 * HD;
    ushort* Wo1lo = u;  u += (size_t)128 * HD;
    ushort* Wo2hi = u;  u += (size_t)128 * 128;
    ushort* Wo2lo = u;  u += (size_t)128 * 128;
    ushort* W1hi  = u;  u += (size_t)128 * 128;
    ushort* W1lo  = u;  u += (size_t)128 * 128;
    ushort* W2hi  = u;  u += (size_t)128 * 128;
    ushort* W2lo  = u;  u += (size_t)128 * 128;

    split_kernel<<<dim3(256, 8), 256, 0, stream>>>(
        agents, Wq, Wk, Wv, Wo1, Wo2, W1, W2,
        Ahi, Alo, Whi, Wlo, Wo1hi, Wo1lo, Wo2hi, Wo2lo, W1hi, W1lo, W2hi, W2lo);
    proj_mfma_kernel<<<dim3(32, 36), 256, 0, stream>>>(Ahi, Alo, Whi, Wlo, R, ps);
    attn_mfma_kernel<<<dim3(64, 6, 2), 64, 0, stream>>>(R, ps, gq, bq, gk, bk, gv, bv, Ohi, Olo);
    wo1_mfma_kernel<<<dim3(32, 8, 3), 256, 0, stream>>>(Ohi, Olo, Wo1hi, Wo1lo, Pp);
    epilogue_mfma_kernel<<<128, 256, 0, stream>>>(Pp, Ahi, Alo, agents, go, bo,
                                                  Wo2hi, Wo2lo, W1hi, W1lo, gn, bn,
                                                  W2hi, W2lo, out);
}

// Round 11
// 159.817 us; speedup vs baseline: 1.5840x; 1.0039x over previous
//
#include <hip/hip_runtime.h>
#include <math.h>

#define NN 2048      // nodes
#define HH 6         // heads
#define HD 768       // H*D
#define NA 32        // agents/scene
#define NB 64        // scenes

typedef __bf16 bf16x8 __attribute__((ext_vector_type(8)));
typedef float  f32x4  __attribute__((ext_vector_type(4)));

// split f into bf16 hi + bf16 lo (truncation; hi+lo ~ 2^-17 relative)
__device__ __forceinline__ void split2(float f, ushort& h, ushort& l) {
    const uint u = __float_as_uint(f);
    h = (ushort)(u >> 16);
    const float hf = __uint_as_float((uint)h << 16);
    l = (ushort)(__float_as_uint(f - hf) >> 16);
}

__device__ __forceinline__ bf16x8 pack8(const ushort* s) {
    uint4 u;
    u.x = (uint)s[0] | ((uint)s[1] << 16);
    u.y = (uint)s[2] | ((uint)s[3] << 16);
    u.z = (uint)s[4] | ((uint)s[5] << 16);
    u.w = (uint)s[6] | ((uint)s[7] << 16);
    return *(bf16x8*)&u;
}

// load 8 fp32, apply LN (gamma/beta), split to bf16 hi/lo fragments
__device__ __forceinline__ void ln8_split(
    const float* __restrict__ x, float mu, float rs,
    const float* __restrict__ g, const float* __restrict__ b,
    bf16x8& hi, bf16x8& lo)
{
    const float4 x0 = *(const float4*)x;
    const float4 x1 = *(const float4*)(x + 4);
    const float4 g0 = *(const float4*)g;
    const float4 g1 = *(const float4*)(g + 4);
    const float4 b0 = *(const float4*)b;
    const float4 b1 = *(const float4*)(b + 4);
    ushort hh[8], ll[8];
    float v;
    v = (x0.x - mu) * rs * g0.x + b0.x; split2(v, hh[0], ll[0]);
    v = (x0.y - mu) * rs * g0.y + b0.y; split2(v, hh[1], ll[1]);
    v = (x0.z - mu) * rs * g0.z + b0.z; split2(v, hh[2], ll[2]);
    v = (x0.w - mu) * rs * g0.w + b0.w; split2(v, hh[3], ll[3]);
    v = (x1.x - mu) * rs * g1.x + b1.x; split2(v, hh[4], ll[4]);
    v = (x1.y - mu) * rs * g1.y + b1.y; split2(v, hh[5], ll[5]);
    v = (x1.z - mu) * rs * g1.z + b1.z; split2(v, hh[6], ll[6]);
    v = (x1.w - mu) * rs * g1.w + b1.w; split2(v, hh[7], ll[7]);
    hi = pack8(hh); lo = pack8(ll);
}

// ---------------------------------------------------------------------------
// K0: split agents / Wq / Wk / Wv / Wo1 / Wo2 / W1 / W2 into bf16 hi+lo.
// ---------------------------------------------------------------------------
__global__ __launch_bounds__(256) void split_kernel(
    const float* __restrict__ agents, const float* __restrict__ Wq,
    const float* __restrict__ Wk, const float* __restrict__ Wv,
    const float* __restrict__ Wo1, const float* __restrict__ Wo2,
    const float* __restrict__ W1, const float* __restrict__ W2,
    ushort* __restrict__ Ahi, ushort* __restrict__ Alo,
    ushort* __restrict__ Whi, ushort* __restrict__ Wlo,
    ushort* __restrict__ Wo1hi, ushort* __restrict__ Wo1lo,
    ushort* __restrict__ Wo2hi, ushort* __restrict__ Wo2lo,
    ushort* __restrict__ W1hi, ushort* __restrict__ W1lo,
    ushort* __restrict__ W2hi, ushort* __restrict__ W2lo)
{
    const int y = blockIdx.y;
    const float* src;
    ushort *dh, *dl;
    int n4;
    switch (y) {
        case 0:  src = agents; dh = Ahi;   dl = Alo;   n4 = NN * 128 / 4;  break;
        case 1:  src = Wq;  dh = Whi;                dl = Wlo;                n4 = 768*128/4; break;
        case 2:  src = Wk;  dh = Whi + 768*128;      dl = Wlo + 768*128;      n4 = 768*128/4; break;
        case 3:  src = Wv;  dh = Whi + 2*768*128;    dl = Wlo + 2*768*128;    n4 = 768*128/4; break;
        case 4:  src = Wo1; dh = Wo1hi; dl = Wo1lo;  n4 = 128 * HD / 4;  break;
        case 5:  src = Wo2; dh = Wo2hi; dl = Wo2lo;  n4 = 128 * 128 / 4; break;
        case 6:  src = W1;  dh = W1hi;  dl = W1lo;   n4 = 128 * 128 / 4; break;
        default: src = W2;  dh = W2hi;  dl = W2lo;   n4 = 128 * 128 / 4; break;
    }
    const int i = blockIdx.x * 256 + threadIdx.x;
    if (i < n4) {
        const float4 v = ((const float4*)src)[i];
        ushort4 h, l;
        split2(v.x, h.x, l.x);
        split2(v.y, h.y, l.y);
        split2(v.z, h.z, l.z);
        split2(v.w, h.w, l.w);
        ((ushort4*)dh)[i] = h;
        ((ushort4*)dl)[i] = l;
    }
}

// ---------------------------------------------------------------------------
// K1: R[m][node][c] = agents @ Wm^T via bf16x3 MFMA + per-64-col LN partials.
// Grid (32, 36) x 256 thr. ps layout [3][NN][12][2] (partial {sum, sumsq}).
// ---------------------------------------------------------------------------
__global__ __launch_bounds__(256) void proj_mfma_kernel(
    const ushort* __restrict__ Ahi, const ushort* __restrict__ Alo,
    const ushort* __restrict__ Whi, const ushort* __restrict__ Wlo,
    float* __restrict__ R, float* __restrict__ ps)
{
    const int tid = threadIdx.x;
    const int wave = tid >> 6, lane = tid & 63;
    const int row0 = blockIdx.x * 64 + wave * 16;
    const int cb0  = blockIdx.y * 64;
    const int m0   = blockIdx.y / 12, pb = blockIdx.y % 12;
    const int lrow = lane & 15, kq = lane >> 4;
    const int koff = kq * 8;

    const ushort* ah = Ahi + (size_t)(row0 + lrow) * 128 + koff;
    const ushort* al = Alo + (size_t)(row0 + lrow) * 128 + koff;

    f32x4 acc[4];
    #pragma unroll
    for (int ct = 0; ct < 4; ++ct)
        #pragma unroll
        for (int j = 0; j < 4; ++j) acc[ct][j] = 0.f;

    #pragma unroll
    for (int kt = 0; kt < 4; ++kt) {
        const bf16x8 avh = *(const bf16x8*)(ah + kt * 32);
        const bf16x8 avl = *(const bf16x8*)(al + kt * 32);
        #pragma unroll
        for (int ct = 0; ct < 4; ++ct) {
            const size_t wof = (size_t)(cb0 + ct * 16 + lrow) * 128 + koff + kt * 32;
            const bf16x8 bvh = *(const bf16x8*)(Whi + wof);
            const bf16x8 bvl = *(const bf16x8*)(Wlo + wof);
            acc[ct] = __builtin_amdgcn_mfma_f32_16x16x32_bf16(avh, bvh, acc[ct], 0, 0, 0);
            acc[ct] = __builtin_amdgcn_mfma_f32_16x16x32_bf16(avh, bvl, acc[ct], 0, 0, 0);
            acc[ct] = __builtin_amdgcn_mfma_f32_16x16x32_bf16(avl, bvh, acc[ct], 0, 0, 0);
        }
    }

    // D: col = lane&15, row = (lane>>4)*4 + j
    const int cloc = cb0 - m0 * 768;   // col base within matrix m0
    #pragma unroll
    for (int ct = 0; ct < 4; ++ct) {
        const int c = cloc + ct * 16 + lrow;
        float* rp = R + ((size_t)m0 * NN + row0 + kq * 4) * HD + c;
        #pragma unroll
        for (int j = 0; j < 4; ++j)
            rp[(size_t)j * HD] = acc[ct][j];
    }

    // per-row partial LN stats over this block's 64 cols
    #pragma unroll
    for (int j = 0; j < 4; ++j) {
        float sj = acc[0][j] + acc[1][j] + acc[2][j] + acc[3][j];
        float qj = acc[0][j] * acc[0][j] + acc[1][j] * acc[1][j]
                 + acc[2][j] * acc[2][j] + acc[3][j] * acc[3][j];
        #pragma unroll
        for (int msk = 1; msk <= 8; msk <<= 1) {
            sj += __shfl_xor(sj, msk);
            qj += __shfl_xor(qj, msk);
        }
        if (lrow == 0) {
            const size_t o = ((size_t)m0 * NN + row0 + kq * 4 + j) * 24 + pb * 2;
            ps[o]     = sj;
            ps[o + 1] = qj;
        }
    }
}

// ---------------------------------------------------------------------------
// K2: fused attention + Wo1 projection. Block = (scene, head), 128 thr:
// wave rt handles query rows [rt*16, rt*16+16). QK^T -> softmax -> PV keeps
// O in registers; O transposed via LDS to A-frag; P_head = O @ Wo1_head^T
// written as per-head K-split partials P[6][2048][128] (no atomics).
// ---------------------------------------------------------------------------
__global__ __launch_bounds__(128) void attn_wo1_kernel(
    const float* __restrict__ R, const float* __restrict__ ps,
    const float* __restrict__ gq, const float* __restrict__ bq,
    const float* __restrict__ gk, const float* __restrict__ bk,
    const float* __restrict__ gv, const float* __restrict__ bv,
    const ushort* __restrict__ Wo1hi, const ushort* __restrict__ Wo1lo,
    float* __restrict__ P)
{
    __shared__ float stat_s[3][32][2];
    __shared__ ushort phi[2][16][40];
    __shared__ ushort plo[2][16][40];
    __shared__ float ob[2][16][140];   // pitch 140: <=2-way conflicts
    const int tid = threadIdx.x;
    const int rt = tid >> 6, lane = tid & 63;
    const int lrow = lane & 15, kq = lane >> 4;
    const int scene = blockIdx.x, h = blockIdx.y;
    const int brow = scene * 32;

    const float* Rq = R;
    const float* Rk = R + (size_t)NN * HD;
    const float* Rv = R + (size_t)2 * NN * HD;

    // combine 12 LN partials per row into LDS {mu, rstd}
    if (tid < 96) {
        const int m = tid >> 5, row = tid & 31;
        const float4* pv = (const float4*)(ps + ((size_t)m * NN + brow + row) * 24);
        float s = 0.f, q = 0.f;
        #pragma unroll
        for (int c = 0; c < 6; ++c) {
            const float4 v = pv[c];
            s += v.x + v.z;
            q += v.y + v.w;
        }
        const float mu  = s * (1.f / 768.f);
        const float var = q * (1.f / 768.f) - mu * mu;
        stat_s[m][row][0] = mu;
        stat_s[m][row][1] = rsqrtf(var + 1e-5f);
    }
    __syncthreads();

    const int qrow = brow + rt * 16 + lrow;
    const float muq = stat_s[0][rt * 16 + lrow][0];
    const float rsq = stat_s[0][rt * 16 + lrow][1];
    float muk[2], rsk[2];
    #pragma unroll
    for (int ct = 0; ct < 2; ++ct) {
        muk[ct] = stat_s[1][ct * 16 + lrow][0];
        rsk[ct] = stat_s[1][ct * 16 + lrow][1];
    }
    float muv[8], rsv[8];
    #pragma unroll
    for (int j = 0; j < 8; ++j) {
        muv[j] = stat_s[2][kq * 8 + j][0];
        rsv[j] = stat_s[2][kq * 8 + j][1];
    }

    // S = Q K^T (16 queries x 32 keys), LN fused into fragment builds
    f32x4 s[2];
    #pragma unroll
    for (int ct = 0; ct < 2; ++ct)
        #pragma unroll
        for (int j = 0; j < 4; ++j) s[ct][j] = 0.f;

    #pragma unroll
    for (int kt = 0; kt < 4; ++kt) {
        const int c0 = h * 128 + kt * 32 + kq * 8;
        bf16x8 qh, ql;
        ln8_split(Rq + (size_t)qrow * HD + c0, muq, rsq, gq + c0, bq + c0, qh, ql);
        #pragma unroll
        for (int ct = 0; ct < 2; ++ct) {
            bf16x8 kh, kl;
            ln8_split(Rk + (size_t)(brow + ct * 16 + lrow) * HD + c0, muk[ct], rsk[ct],
                      gk + c0, bk + c0, kh, kl);
            s[ct] = __builtin_amdgcn_mfma_f32_16x16x32_bf16(qh, kh, s[ct], 0, 0, 0);
            s[ct] = __builtin_amdgcn_mfma_f32_16x16x32_bf16(qh, kl, s[ct], 0, 0, 0);
            s[ct] = __builtin_amdgcn_mfma_f32_16x16x32_bf16(ql, kh, s[ct], 0, 0, 0);
        }
    }

    // row softmax over 32 keys (row = kq*4+j; cols spread over lrow x 2 ct)
    const float scl = 0.08838834764831845f;  // 1/sqrt(128)
    float p0[4], p1[4];
    #pragma unroll
    for (int j = 0; j < 4; ++j) {
        const float a = s[0][j] * scl, b = s[1][j] * scl;
        float m = fmaxf(a, b);
        #pragma unroll
        for (int msk = 1; msk <= 8; msk <<= 1) m = fmaxf(m, __shfl_xor(m, msk));
        const float ea = __expf(a - m), eb = __expf(b - m);
        float su = ea + eb;
        #pragma unroll
        for (int msk = 1; msk <= 8; msk <<= 1) su += __shfl_xor(su, msk);
        const float inv = 1.f / su;
        p0[j] = ea * inv;
        p1[j] = eb * inv;
    }

    // transpose P-attn to A-frag layout via LDS (per-wave buffer)
    #pragma unroll
    for (int j = 0; j < 4; ++j) {
        ushort hh, ll;
        split2(p0[j], hh, ll);
        phi[rt][kq * 4 + j][lrow] = hh;
        plo[rt][kq * 4 + j][lrow] = ll;
        split2(p1[j], hh, ll);
        phi[rt][kq * 4 + j][16 + lrow] = hh;
        plo[rt][kq * 4 + j][16 + lrow] = ll;
    }
    __syncthreads();
    const bf16x8 pah = *(const bf16x8*)&phi[rt][lrow][kq * 8];
    const bf16x8 pal = *(const bf16x8*)&plo[rt][lrow][kq * 8];

    // O = P V over 8 d-tiles, kept in registers (C-layout)
    f32x4 o[8];
    #pragma unroll
    for (int dt = 0; dt < 8; ++dt) {
        const int d = h * 128 + dt * 16 + lrow;
        const float gvd = gv[d], bvd = bv[d];
        ushort vh[8], vl[8];
        #pragma unroll
        for (int j = 0; j < 8; ++j) {
            const float x = Rv[(size_t)(brow + kq * 8 + j) * HD + d];
            const float v = fmaxf((x - muv[j]) * rsv[j] * gvd + bvd, 0.f);
            split2(v, vh[j], vl[j]);
        }
        const bf16x8 bh = pack8(vh), bl = pack8(vl);
        #pragma unroll
        for (int j = 0; j < 4; ++j) o[dt][j] = 0.f;
        o[dt] = __builtin_amdgcn_mfma_f32_16x16x32_bf16(pah, bh, o[dt], 0, 0, 0);
        o[dt] = __builtin_amdgcn_mfma_f32_16x16x32_bf16(pah, bl, o[dt], 0, 0, 0);
        o[dt] = __builtin_amdgcn_mfma_f32_16x16x32_bf16(pal, bh, o[dt], 0, 0, 0);
    }

    // transpose O (C-layout: row=kq*4+j, col=dt*16+lrow) to A-frag via LDS
    #pragma unroll
    for (int dt = 0; dt < 8; ++dt)
        #pragma unroll
        for (int j = 0; j < 4; ++j)
            ob[rt][kq * 4 + j][dt * 16 + lrow] = o[dt][j];
    __syncthreads();

    bf16x8 oh[4], ol[4];
    #pragma unroll
    for (int kt = 0; kt < 4; ++kt) {
        const float4 z0 = *(const float4*)&ob[rt][lrow][kt * 32 + kq * 8];
        const float4 z1 = *(const float4*)&ob[rt][lrow][kt * 32 + kq * 8 + 4];
        const float zz[8] = {z0.x, z0.y, z0.z, z0.w, z1.x, z1.y, z1.z, z1.w};
        ushort hh[8], ll[8];
        #pragma unroll
        for (int j = 0; j < 8; ++j) split2(zz[j], hh[j], ll[j]);
        oh[kt] = pack8(hh); ol[kt] = pack8(ll);
    }

    // P_head = O @ Wo1[:, h*128:+128]^T  (8 col-tiles x 4 k-tiles x 3 MFMA)
    #pragma unroll
    for (int ct = 0; ct < 8; ++ct) {
        f32x4 p2;
        #pragma unroll
        for (int j = 0; j < 4; ++j) p2[j] = 0.f;
        const size_t wb = (size_t)(ct * 16 + lrow) * HD + h * 128;
        #pragma unroll
        for (int kt = 0; kt < 4; ++kt) {
            const int c0 = kt * 32 + kq * 8;
            const bf16x8 wh = *(const bf16x8*)(Wo1hi + wb + c0);
            const bf16x8 wl = *(const bf16x8*)(Wo1lo + wb + c0);
            p2 = __builtin_amdgcn_mfma_f32_16x16x32_bf16(oh[kt], wh, p2, 0, 0, 0);
            p2 = __builtin_amdgcn_mfma_f32_16x16x32_bf16(oh[kt], wl, p2, 0, 0, 0);
            p2 = __builtin_amdgcn_mfma_f32_16x16x32_bf16(ol[kt], wh, p2, 0, 0, 0);
        }
        float* pp = P + ((size_t)h * NN + brow + rt * 16 + kq * 4) * 128 + ct * 16 + lrow;
        #pragma unroll
        for (int j = 0; j < 4; ++j)
            pp[(size_t)j * 128] = p2[j];
    }
}

// ---------------------------------------------------------------------------
// K3: fused epilogue, 4 waves / block, 16 nodes / block, grid 128.
//  t = relu(LN(sum_h P[h])) in A-frag layout; u = t@Wo2^T + A@W1^T;
//  z = relu(LN(u)) cross-wave; out = relu(z@W2^T + A).
// ---------------------------------------------------------------------------
__global__ __launch_bounds__(256) void epilogue_mfma_kernel(
    const float* __restrict__ P,
    const ushort* __restrict__ Ahi, const ushort* __restrict__ Alo,
    const float* __restrict__ agents,
    const float* __restrict__ go, const float* __restrict__ bo,
    const ushort* __restrict__ Wo2hi, const ushort* __restrict__ Wo2lo,
    const ushort* __restrict__ W1hi, const ushort* __restrict__ W1lo,
    const float* __restrict__ gn, const float* __restrict__ bn,
    const ushort* __restrict__ W2hi, const ushort* __restrict__ W2lo,
    float* __restrict__ out)
{
    __shared__ float zb[16][132];
    __shared__ float red2[4][16][2];
    const int tid = threadIdx.x;
    const int wave = tid >> 6, lane = tid & 63;
    const int lrow = lane & 15, kq = lane >> 4;
    const int n0 = blockIdx.x * 16;
    const int nodeA = n0 + lrow;

    // ---- t = relu(LN(sum_h P[h])), A-frag layout ----
    float tv[4][8];
    float s = 0.f, q = 0.f;
    #pragma unroll
    for (int kt = 0; kt < 4; ++kt) {
        const int c0 = kt * 32 + kq * 8;
        const size_t base = (size_t)nodeA * 128 + c0;
        #pragma unroll
        for (int hf = 0; hf < 2; ++hf) {
            float ax = 0.f, ay = 0.f, az = 0.f, aw = 0.f;
            #pragma unroll
            for (int head = 0; head < 6; ++head) {
                const float4 v = *(const float4*)(P + (size_t)head * NN * 128 + base + hf * 4);
                ax += v.x; ay += v.y; az += v.z; aw += v.w;
            }
            tv[kt][hf * 4 + 0] = ax;
            tv[kt][hf * 4 + 1] = ay;
            tv[kt][hf * 4 + 2] = az;
            tv[kt][hf * 4 + 3] = aw;
        }
        #pragma unroll
        for (int j = 0; j < 8; ++j) { s += tv[kt][j]; q += tv[kt][j] * tv[kt][j]; }
    }
    s += __shfl_xor(s, 16); s += __shfl_xor(s, 32);
    q += __shfl_xor(q, 16); q += __shfl_xor(q, 32);
    const float mu = s * (1.f / 128.f);
    const float rs = rsqrtf(q * (1.f / 128.f) - mu * mu + 1e-5f);

    bf16x8 th[4], tl[4], ah[4], al[4];
    #pragma unroll
    for (int kt = 0; kt < 4; ++kt) {
        const int c0 = kt * 32 + kq * 8;
        const float4 g0 = *(const float4*)(go + c0);
        const float4 g1 = *(const float4*)(go + c0 + 4);
        const float4 b0 = *(const float4*)(bo + c0);
        const float4 b1 = *(const float4*)(bo + c0 + 4);
        const float gg[8] = {g0.x, g0.y, g0.z, g0.w, g1.x, g1.y, g1.z, g1.w};
        const float bb[8] = {b0.x, b0.y, b0.z, b0.w, b1.x, b1.y, b1.z, b1.w};
        ushort hh[8], ll[8];
        #pragma unroll
        for (int j = 0; j < 8; ++j) {
            const float v = fmaxf((tv[kt][j] - mu) * rs * gg[j] + bb[j], 0.f);
            split2(v, hh[j], ll[j]);
        }
        th[kt] = pack8(hh); tl[kt] = pack8(ll);
        ah[kt] = *(const bf16x8*)(Ahi + (size_t)nodeA * 128 + c0);
        al[kt] = *(const bf16x8*)(Alo + (size_t)nodeA * 128 + c0);
    }

    // ---- u = t@Wo2^T + A@W1^T  (this wave's 2 col-tiles) ----
    f32x4 u[2];
    #pragma unroll
    for (int ct2 = 0; ct2 < 2; ++ct2)
        #pragma unroll
        for (int j = 0; j < 4; ++j) u[ct2][j] = 0.f;

    #pragma unroll
    for (int ct2 = 0; ct2 < 2; ++ct2) {
        const int ct = wave * 2 + ct2;
        const size_t wb = (size_t)(ct * 16 + lrow) * 128;
        #pragma unroll
        for (int kt = 0; kt < 4; ++kt) {
            const int c0 = kt * 32 + kq * 8;
            const bf16x8 wh = *(const bf16x8*)(Wo2hi + wb + c0);
            const bf16x8 wl = *(const bf16x8*)(Wo2lo + wb + c0);
            const bf16x8 vh = *(const bf16x8*)(W1hi + wb + c0);
            const bf16x8 vl = *(const bf16x8*)(W1lo + wb + c0);
            u[ct2] = __builtin_amdgcn_mfma_f32_16x16x32_bf16(th[kt], wh, u[ct2], 0, 0, 0);
            u[ct2] = __builtin_amdgcn_mfma_f32_16x16x32_bf16(th[kt], wl, u[ct2], 0, 0, 0);
            u[ct2] = __builtin_amdgcn_mfma_f32_16x16x32_bf16(tl[kt], wh, u[ct2], 0, 0, 0);
            u[ct2] = __builtin_amdgcn_mfma_f32_16x16x32_bf16(ah[kt], vh, u[ct2], 0, 0, 0);
            u[ct2] = __builtin_amdgcn_mfma_f32_16x16x32_bf16(ah[kt], vl, u[ct2], 0, 0, 0);
            u[ct2] = __builtin_amdgcn_mfma_f32_16x16x32_bf16(al[kt], vh, u[ct2], 0, 0, 0);
        }
    }

    // ---- z = relu(LN(u)): cross-wave reduction via LDS ----
    #pragma unroll
    for (int j = 0; j < 4; ++j) {
        float s2 = u[0][j] + u[1][j];
        float q2 = u[0][j] * u[0][j] + u[1][j] * u[1][j];
        #pragma unroll
        for (int msk = 1; msk <= 8; msk <<= 1) {
            s2 += __shfl_xor(s2, msk);
            q2 += __shfl_xor(q2, msk);
        }
        if (lrow == 0) {
            red2[wave][kq * 4 + j][0] = s2;
            red2[wave][kq * 4 + j][1] = q2;
        }
    }
    __syncthreads();
    #pragma unroll
    for (int j = 0; j < 4; ++j) {
        const int row = kq * 4 + j;
        const float s2t = red2[0][row][0] + red2[1][row][0] + red2[2][row][0] + red2[3][row][0];
        const float q2t = red2[0][row][1] + red2[1][row][1] + red2[2][row][1] + red2[3][row][1];
        const float mu2 = s2t * (1.f / 128.f);
        const float rs2 = rsqrtf(q2t * (1.f / 128.f) - mu2 * mu2 + 1e-5f);
        #pragma unroll
        for (int ct2 = 0; ct2 < 2; ++ct2) {
            const int c = (wave * 2 + ct2) * 16 + lrow;
            zb[row][c] = fmaxf((u[ct2][j] - mu2) * rs2 * gn[c] + bn[c], 0.f);
        }
    }
    __syncthreads();

    // ---- out = relu(z@W2^T + A)  (this wave's 2 col-tiles) ----
    bf16x8 zh[4], zl[4];
    #pragma unroll
    for (int kt = 0; kt < 4; ++kt) {
        const int c0 = kt * 32 + kq * 8;
        const float4 z0 = *(const float4*)&zb[lrow][c0];
        const float4 z1 = *(const float4*)&zb[lrow][c0 + 4];
        const float zz[8] = {z0.x, z0.y, z0.z, z0.w, z1.x, z1.y, z1.z, z1.w};
        ushort hh[8], ll[8];
        #pragma unroll
        for (int j = 0; j < 8; ++j) split2(zz[j], hh[j], ll[j]);
        zh[kt] = pack8(hh); zl[kt] = pack8(ll);
    }
    #pragma unroll
    for (int ct2 = 0; ct2 < 2; ++ct2) {
        const int ct = wave * 2 + ct2;
        f32x4 o;
        #pragma unroll
        for (int j = 0; j < 4; ++j) o[j] = 0.f;
        const size_t wb = (size_t)(ct * 16 + lrow) * 128;
        #pragma unroll
        for (int kt = 0; kt < 4; ++kt) {
            const int c0 = kt * 32 + kq * 8;
            const bf16x8 wh = *(const bf16x8*)(W2hi + wb + c0);
            const bf16x8 wl = *(const bf16x8*)(W2lo + wb + c0);
            o = __builtin_amdgcn_mfma_f32_16x16x32_bf16(zh[kt], wh, o, 0, 0, 0);
            o = __builtin_amdgcn_mfma_f32_16x16x32_bf16(zh[kt], wl, o, 0, 0, 0);
            o = __builtin_amdgcn_mfma_f32_16x16x32_bf16(zl[kt], wh, o, 0, 0, 0);
        }
        #pragma unroll
        for (int j = 0; j < 4; ++j) {
            const size_t oo = (size_t)(n0 + kq * 4 + j) * 128 + ct * 16 + lrow;
            out[oo] = fmaxf(o[j] + agents[oo], 0.f);
        }
    }
}

// ---------------------------------------------------------------------------
extern "C" void kernel_launch(void* const* d_in, const int* in_sizes, int n_in,
                              void* d_out, int out_size, void* d_ws, size_t ws_size,
                              hipStream_t stream) {
    (void)in_sizes; (void)n_in; (void)out_size; (void)ws_size;
    const float* agents = (const float*)d_in[0];
    const float* Wq  = (const float*)d_in[3];
    const float* gq  = (const float*)d_in[4];
    const float* bq  = (const float*)d_in[5];
    const float* Wk  = (const float*)d_in[6];
    const float* gk  = (const float*)d_in[7];
    const float* bk  = (const float*)d_in[8];
    const float* Wv  = (const float*)d_in[9];
    const float* gv  = (const float*)d_in[10];
    const float* bv  = (const float*)d_in[11];
    const float* Wo1 = (const float*)d_in[12];
    const float* go  = (const float*)d_in[13];
    const float* bo  = (const float*)d_in[14];
    const float* Wo2 = (const float*)d_in[15];
    const float* W1  = (const float*)d_in[16];
    const float* gn  = (const float*)d_in[17];
    const float* bn  = (const float*)d_in[18];
    const float* W2  = (const float*)d_in[19];
    float* out = (float*)d_out;

    float* ws = (float*)d_ws;
    float* R  = ws;                                   // 3*NN*HD fp32
    float* Pp = R + (size_t)3 * NN * HD;              // 6*NN*128 fp32
    float* ps = Pp + (size_t)6 * NN * 128;            // 3*NN*24 fp32 partials
    ushort* u = (ushort*)(ps + (size_t)3 * NN * 24);  // 16B-aligned bf16 zone
    ushort* Ahi   = u;  u += (size_t)NN * 128;
    ushort* Alo   = u;  u += (size_t)NN * 128;
    ushort* Whi   = u;  u += (size_t)3 * 768 * 128;
    ushort* Wlo   = u;  u += (size_t)3 * 768 * 128;
    ushort* Wo1hi = u;  u += (size_t)128 * HD;
    ushort* Wo1lo = u;  u += (size_t)128 * HD;
    ushort* Wo2hi = u;  u += (size_t)128 * 128;
    ushort* Wo2lo = u;  u += (size_t)128 * 128;
    ushort* W1hi  = u;  u += (size_t)128 * 128;
    ushort* W1lo  = u;  u += (size_t)128 * 128;
    ushort* W2hi  = u;  u += (size_t)128 * 128;
    ushort* W2lo  = u;  u += (size_t)128 * 128;

    split_kernel<<<dim3(256, 8), 256, 0, stream>>>(
        agents, Wq, Wk, Wv, Wo1, Wo2, W1, W2,
        Ahi, Alo, Whi, Wlo, Wo1hi, Wo1lo, Wo2hi, Wo2lo, W1hi, W1lo, W2hi, W2lo);
    proj_mfma_kernel<<<dim3(32, 36), 256, 0, stream>>>(Ahi, Alo, Whi, Wlo, R, ps);
    attn_wo1_kernel<<<dim3(NB, HH), 128, 0, stream>>>(R, ps, gq, bq, gk, bk, gv, bv,
                                                      Wo1hi, Wo1lo, Pp);
    epilogue_mfma_kernel<<<128, 256, 0, stream>>>(Pp, Ahi, Alo, agents, go, bo,
                                                  Wo2hi, Wo2lo, W1hi, W1lo, gn, bn,
                                                  W2hi, W2lo, out);
}